// Round 7
// baseline (374.266 us; speedup 1.0000x reference)
//
#include <hip/hip_runtime.h>
#include <hip/hip_fp16.h>
#include <math.h>

#define N_NODES 10000
#define N_EDGES 160000
#define N_GRAPHS 64

using half8 = __attribute__((ext_vector_type(8))) _Float16;
using floatx4 = __attribute__((ext_vector_type(4))) float;

// raw f16 fragment word: 4 halfs (NV=1) or 8 halfs (NV=2)
template <int NV> struct KW;
template <> struct KW<1> { using T = uint2; };
template <> struct KW<2> { using T = uint4; };

__device__ inline void cvt_kv(const uint2& w, float4* dst) {
  float2 a = __half22float2(*reinterpret_cast<const __half2*>(&w.x));
  float2 b = __half22float2(*reinterpret_cast<const __half2*>(&w.y));
  dst[0] = make_float4(a.x, a.y, b.x, b.y);
}
__device__ inline void cvt_kv(const uint4& w, float4* dst) {
  float2 a = __half22float2(*reinterpret_cast<const __half2*>(&w.x));
  float2 b = __half22float2(*reinterpret_cast<const __half2*>(&w.y));
  float2 c = __half22float2(*reinterpret_cast<const __half2*>(&w.z));
  float2 d = __half22float2(*reinterpret_cast<const __half2*>(&w.w));
  dst[0] = make_float4(a.x, a.y, b.x, b.y);
  dst[1] = make_float4(c.x, c.y, d.x, d.y);
}

// interleaved KV: lane-block b holds [K 4NV halfs][V 4NV halfs] at b*8NV
__device__ inline void load_kv_pair(const __half* rb, uint2& kr, uint2& vr) {
  uint4 w = *reinterpret_cast<const uint4*>(rb);  // one 16B load: K+V
  kr = make_uint2(w.x, w.y);
  vr = make_uint2(w.z, w.w);
}
__device__ inline void load_kv_pair(const __half* rb, uint4& kr, uint4& vr) {
  kr = *reinterpret_cast<const uint4*>(rb);
  vr = *reinterpret_cast<const uint4*>(rb + 8);
}

// ---------------------------------------------------------------------------
// MFMA GEMM: [Q|G|K|V|S] = A[M,K]_f16 @ Wp_f16 + bias_f32.
// Epilogue stages the 64x64 f16 tile in LDS, then vector-stores:
//   Q/G/S cols -> QS row-major; K/V cols -> KV INTERLEAVED lane-block layout.
// ---------------------------------------------------------------------------
template <int K, int HD, int DOUT>
__global__ __launch_bounds__(256) void gemm_mfma(
    const __half* __restrict__ A, const __half* __restrict__ Wp,
    const float* __restrict__ bias, __half* __restrict__ QS,
    __half* __restrict__ KV, int M) {
  constexpr int QSS = HD + 64 + DOUT;
  constexpr int KVS = 2 * HD;
  constexpr int NV = DOUT / 64;
  constexpr int KS = K / 32;
  __shared__ __half st[64][72];
  const int tid = threadIdx.x;
  const int wave = tid >> 6, lane = tid & 63;
  const int quad = lane >> 4, n16 = lane & 15;
  const int row0 = blockIdx.y * 64;
  const int col0 = blockIdx.x * 64;
  const int nblk0 = blockIdx.x * 4;

  const int arow = min(row0 + wave * 16 + n16, M - 1);
  half8 afrag[KS];
#pragma unroll
  for (int s = 0; s < KS; ++s)
    afrag[s] = *reinterpret_cast<const half8*>(A + (size_t)arow * K + s * 32 + quad * 8);

  floatx4 acc[4];
#pragma unroll
  for (int t = 0; t < 4; ++t) {
    acc[t] = (floatx4){0.f, 0.f, 0.f, 0.f};
#pragma unroll
    for (int s = 0; s < KS; ++s) {
      half8 bf = *reinterpret_cast<const half8*>(
          Wp + (((size_t)(nblk0 + t) * KS + s) * 64 + lane) * 8);
      acc[t] = __builtin_amdgcn_mfma_f32_16x16x32_f16(afrag[s], bf, acc[t], 0, 0, 0);
    }
  }

#pragma unroll
  for (int t = 0; t < 4; ++t) {
    float bv = bias[col0 + t * 16 + n16];
#pragma unroll
    for (int r = 0; r < 4; ++r)
      st[wave * 16 + quad * 4 + r][t * 16 + n16] = __float2half(acc[t][r] + bv);
  }
  __syncthreads();

  if (col0 < HD + 64 || col0 >= 3 * HD + 64) {
    const int qcol = (col0 < HD + 64) ? col0 : (HD + 64 + (col0 - 3 * HD - 64));
    for (int c = tid; c < 512; c += 256) {
      int r = c >> 3, seg = c & 7;
      int row = row0 + r;
      if (row < M)
        *reinterpret_cast<uint4*>(QS + (size_t)row * QSS + qcol + seg * 8) =
            *reinterpret_cast<const uint4*>(&st[r][seg * 8]);
    }
  } else {
    constexpr int G = 4 * NV;       // halfs per lane-chunk
    constexpr int NG = 64 / G;      // chunks per 64-col block
    const int ckv0 = col0 - (HD + 64);  // in [0, 2*HD), block fully K or V
    for (int c = tid; c < 64 * NG; c += 256) {
      int r = c / NG, gl = c % NG;
      int row = row0 + r;
      if (row >= M) continue;
      int ckv = ckv0 + gl * G;
      int off;
      if (ckv < HD) off = (ckv / G) * (2 * G);
      else          off = ((ckv - HD) / G) * (2 * G) + G;
      if (NV == 1)
        *reinterpret_cast<uint2*>(KV + (size_t)row * KVS + off) =
            *reinterpret_cast<const uint2*>(&st[r][gl * G]);
      else
        *reinterpret_cast<uint4*>(KV + (size_t)row * KVS + off) =
            *reinterpret_cast<const uint4*>(&st[r][gl * G]);
    }
  }
}

// ---------------------------------------------------------------------------
// Pack weights into B-fragment order (f16), with fused G columns:
//   Wg[k, h*16+d] = SCALE * sum_c wq[k,h*DOUT+c] * we[d,h*DOUT+c]
// Q columns pre-scaled. Tail range converts x -> f16.
// ---------------------------------------------------------------------------
__device__ inline void pack_layer(int i, int K, int HD, int DOUT, float scale,
                                  const float* wq, const float* wk,
                                  const float* wv, const float* wsk,
                                  const float* we, const float* bq,
                                  const float* bk, const float* bv,
                                  const float* bs, __half* Wp, float* bcat) {
  const int W = 3 * HD + DOUT + 64;
  const int KS = K / 32;
  if (i < K * W) {
    int j = i & 7, lane = (i >> 3) & 63, fs = i >> 9;
    int nblk = fs / KS, s = fs - nblk * KS;
    int quad = lane >> 4, n = lane & 15;
    int k = s * 32 + quad * 8 + j, c = nblk * 16 + n;
    float v;
    if (c < HD) {
      v = wq[k * HD + c] * scale;
    } else if (c < HD + 64) {
      int gi = c - HD, hh = gi >> 4, d = gi & 15;
      float a = 0.f;
      for (int cc = 0; cc < DOUT; ++cc)
        a += wq[k * HD + hh * DOUT + cc] * we[d * HD + hh * DOUT + cc];
      v = a * scale;
    } else if (c < 2 * HD + 64) {
      v = wk[k * HD + (c - HD - 64)];
    } else if (c < 3 * HD + 64) {
      v = wv[k * HD + (c - 2 * HD - 64)];
    } else {
      v = wsk[k * DOUT + (c - 3 * HD - 64)];
    }
    Wp[i] = __float2half(v);
  } else {
    int c = i - K * W;
    float v;
    if (c < HD) {
      v = bq[c] * scale;
    } else if (c < HD + 64) {
      int gi = c - HD, hh = gi >> 4, d = gi & 15;
      float a = 0.f;
      for (int cc = 0; cc < DOUT; ++cc)
        a += bq[hh * DOUT + cc] * we[d * HD + hh * DOUT + cc];
      v = a * scale;
    } else if (c < 2 * HD + 64) {
      v = bk[c - HD - 64];
    } else if (c < 3 * HD + 64) {
      v = bv[c - 2 * HD - 64];
    } else {
      v = bs[c - 3 * HD - 64];
    }
    bcat[c] = v;
  }
}

#define T1 115584            // 128*896 + 896
#define T2 227904            // T1 + 64*1728 + 1728
#define T3 343488            // T2 + 128*896 + 896
#define TCONV (N_NODES * 32) // x float4 count
#define TTOT (T3 + TCONV)

__global__ void pack_all(
    const float* wq1, const float* wk1, const float* wv1, const float* ws1,
    const float* we1, const float* bq1, const float* bk1, const float* bv1,
    const float* bs1,
    const float* wq2, const float* wk2, const float* wv2, const float* ws2,
    const float* we2, const float* bq2, const float* bk2, const float* bv2,
    const float* bs2,
    const float* wq3, const float* wk3, const float* wv3, const float* ws3,
    const float* we3, const float* bq3, const float* bk3, const float* bv3,
    const float* bs3,
    __half* W1, float* b1, __half* W2, float* b2, __half* W3, float* b3,
    const float* x, __half* x16) {
  const float SC1 = 0.125f, SC2 = 0.08838834764831845f;
  for (int i = blockIdx.x * blockDim.x + threadIdx.x; i < TTOT;
       i += gridDim.x * blockDim.x) {
    if (i < T1)
      pack_layer(i, 128, 256, 64, SC1, wq1, wk1, wv1, ws1, we1, bq1, bk1, bv1, bs1, W1, b1);
    else if (i < T2)
      pack_layer(i - T1, 64, 512, 128, SC2, wq2, wk2, wv2, ws2, we2, bq2, bk2, bv2, bs2, W2, b2);
    else if (i < T3)
      pack_layer(i - T2, 128, 256, 64, SC1, wq3, wk3, wv3, ws3, we3, bq3, bk3, bv3, bs3, W3, b3);
    else {
      int k = i - T3;
      float4 v = reinterpret_cast<const float4*>(x)[k];
      __half2* o = reinterpret_cast<__half2*>(x16) + 2 * k;
      o[0] = __floats2half2_rn(v.x, v.y);
      o[1] = __floats2half2_rn(v.z, v.w);
    }
  }
}

// ---------------------------------------------------------------------------
// CSR build over dst
// ---------------------------------------------------------------------------
__global__ void count_dst(const int* __restrict__ dst, int* __restrict__ cnt) {
  int e = blockIdx.x * blockDim.x + threadIdx.x;
  if (e < N_EDGES) atomicAdd(&cnt[dst[e]], 1);
}

__global__ __launch_bounds__(1024) void scan_offs(const int* __restrict__ cnt,
                                                  int* __restrict__ offs) {
  __shared__ int part[1024];
  const int t = threadIdx.x;
  const int chunk = (N_NODES + 1023) / 1024;
  const int b = t * chunk;
  const int e = min(N_NODES, b + chunk);
  int s = 0;
  for (int i = b; i < e; ++i) s += cnt[i];
  part[t] = s;
  __syncthreads();
  for (int off = 1; off < 1024; off <<= 1) {
    int v = (t >= off) ? part[t - off] : 0;
    __syncthreads();
    part[t] += v;
    __syncthreads();
  }
  int pre = (t == 0) ? 0 : part[t - 1];
  for (int i = b; i < e; ++i) { offs[i] = pre; pre += cnt[i]; }
  if (t == 0) offs[N_NODES] = part[1023];
}

__global__ void scatter_csr(const int* __restrict__ src, const int* __restrict__ dst,
                            const float* __restrict__ edge_attr,
                            const int* __restrict__ offs, int* __restrict__ cursor,
                            int* __restrict__ csr_src, float* __restrict__ csr_ea) {
  int e = blockIdx.x * blockDim.x + threadIdx.x;
  if (e < N_EDGES) {
    int d = dst[e];
    int pos = offs[d] + atomicAdd(&cursor[d], 1);
    csr_src[pos] = src[e];
    float4* o4 = reinterpret_cast<float4*>(csr_ea + (size_t)pos * 16);
    const float4* s4 = reinterpret_cast<const float4*>(edge_attr + (size_t)e * 16);
    o4[0] = s4[0]; o4[1] = s4[1]; o4[2] = s4[2]; o4[3] = s4[3];
  }
}

// ---------------------------------------------------------------------------
// Fused edge kernel: 2 WAVES PER NODE (alternating 4-edge groups, stride 8),
// partials combined via LDS. Head-local lanes, folded edge algebra, fp16
// QS/interleaved-KV, ping-pong pipeline, no-max softmax (logits bounded).
// ---------------------------------------------------------------------------
template <int DOUT>
__global__ __launch_bounds__(256) void edge_attn(
    const __half* __restrict__ QS, const __half* __restrict__ KV,
    const float* __restrict__ we, const int* __restrict__ csr_src,
    const float* __restrict__ csr_ea, const int* __restrict__ offs,
    float* __restrict__ out, __half* __restrict__ out16) {
  constexpr int HD = 4 * DOUT;
  constexpr int QSS = HD + 64 + DOUT;
  constexpr int KVS = 2 * HD;
  constexpr int NV = DOUT / 64;
  using KWT = typename KW<NV>::T;

  __shared__ float sacc[2][HD];
  __shared__ float sl[2][64], stc[2][64];

  const int lane = threadIdx.x & 63;
  const int wid = threadIdx.x >> 6;
  const int nl = wid >> 1, half = wid & 1;
  const int h = lane >> 4, t16 = lane & 15;
  const int n = blockIdx.x * 2 + nl;  // N_NODES even
  const int c0 = t16 * 4 * NV;
  const int bofs = (h * 16 + t16) * 8 * NV;  // interleaved KV lane offset

  const __half* base = QS + (size_t)n * QSS;
  float4 q[NV], acc[NV];
  {
    KWT qw = *reinterpret_cast<const KWT*>(base + h * DOUT + c0);
    cvt_kv(qw, q);
  }
#pragma unroll
  for (int v = 0; v < NV; ++v) acc[v] = make_float4(0.f, 0.f, 0.f, 0.f);
  const float g = __half2float(base[HD + h * 16 + t16]);  // pre-scaled G

  float lsum = 0.f, tacc = 0.f;

  const int s0 = offs[n], s1 = offs[n + 1];
  const int end_full = s0 + ((s1 - s0) & ~3);

  int sjA[4], sjB[4];
  float eaA[4], eaB[4];
  KWT krA[4], vrA[4], krB[4], vrB[4];

  auto load_grp = [&](int bi, int (&sj)[4], float (&ea)[4], KWT (&kr)[4],
                      KWT (&vr)[4]) {
#pragma unroll
    for (int j = 0; j < 4; ++j) sj[j] = csr_src[bi + j];
#pragma unroll
    for (int j = 0; j < 4; ++j) ea[j] = csr_ea[(size_t)(bi + j) * 16 + t16];
#pragma unroll
    for (int j = 0; j < 4; ++j)
      load_kv_pair(KV + (size_t)sj[j] * KVS + bofs, kr[j], vr[j]);
  };

  auto compute_grp = [&](float (&ea)[4], KWT (&kr)[4], KWT (&vr)[4]) {
    float a[4];
#pragma unroll
    for (int j = 0; j < 4; ++j) {
      float4 kk[NV];
      cvt_kv(kr[j], kk);
      float p = ea[j] * g;
#pragma unroll
      for (int v = 0; v < NV; ++v)
        p += q[v].x * kk[v].x + q[v].y * kk[v].y + q[v].z * kk[v].z +
             q[v].w * kk[v].w;
      a[j] = p;
    }
#pragma unroll
    for (int j = 0; j < 4; ++j) {
      a[j] += __shfl_xor(a[j], 1);
      a[j] += __shfl_xor(a[j], 2);
      a[j] += __shfl_xor(a[j], 4);
      a[j] += __shfl_xor(a[j], 8);
    }
    float p0 = __expf(a[0]), p1 = __expf(a[1]);
    float p2 = __expf(a[2]), p3 = __expf(a[3]);
    lsum += p0 + p1 + p2 + p3;
    tacc += p0 * ea[0] + p1 * ea[1] + p2 * ea[2] + p3 * ea[3];
    float pj[4] = {p0, p1, p2, p3};
#pragma unroll
    for (int j = 0; j < 4; ++j) {
      float4 vv[NV];
      cvt_kv(vr[j], vv);
#pragma unroll
      for (int v = 0; v < NV; ++v) {
        acc[v].x += pj[j] * vv[v].x;
        acc[v].y += pj[j] * vv[v].y;
        acc[v].z += pj[j] * vv[v].z;
        acc[v].w += pj[j] * vv[v].w;
      }
    }
  };

  int ii = s0 + half * 4;
  if (ii < end_full) {
    load_grp(ii, sjA, eaA, krA, vrA);
    for (;;) {
      int nx = ii + 8;
      if (nx >= end_full) { compute_grp(eaA, krA, vrA); break; }
      load_grp(nx, sjB, eaB, krB, vrB);
      compute_grp(eaA, krA, vrA);
      ii = nx; nx = ii + 8;
      if (nx >= end_full) { compute_grp(eaB, krB, vrB); break; }
      load_grp(nx, sjA, eaA, krA, vrA);
      compute_grp(eaB, krB, vrB);
      ii = nx;
    }
  }

  if (half == 0) {
    for (int t = end_full; t < s1; ++t) {
      int s = csr_src[t];
      float ea0 = csr_ea[(size_t)t * 16 + t16];
      KWT kw, vw;
      load_kv_pair(KV + (size_t)s * KVS + bofs, kw, vw);
      float4 kk[NV], vv[NV];
      cvt_kv(kw, kk);
      cvt_kv(vw, vv);
      float a = ea0 * g;
#pragma unroll
      for (int v = 0; v < NV; ++v)
        a += q[v].x * kk[v].x + q[v].y * kk[v].y + q[v].z * kk[v].z + q[v].w * kk[v].w;
      a += __shfl_xor(a, 1);
      a += __shfl_xor(a, 2);
      a += __shfl_xor(a, 4);
      a += __shfl_xor(a, 8);
      float p = __expf(a);
      lsum += p;
      tacc += p * ea0;
#pragma unroll
      for (int v = 0; v < NV; ++v) {
        acc[v].x += p * vv[v].x;
        acc[v].y += p * vv[v].y;
        acc[v].z += p * vv[v].z;
        acc[v].w += p * vv[v].w;
      }
    }
  }

  // combine the two waves' partials via LDS
  if (half == 1) {
#pragma unroll
    for (int v = 0; v < NV; ++v) {
      int cb = h * DOUT + c0 + 4 * v;
      sacc[nl][cb + 0] = acc[v].x;
      sacc[nl][cb + 1] = acc[v].y;
      sacc[nl][cb + 2] = acc[v].z;
      sacc[nl][cb + 3] = acc[v].w;
    }
    sl[nl][lane] = lsum;
    stc[nl][lane] = tacc;
  }
  __syncthreads();
  if (half != 0) return;

  lsum += sl[nl][lane];
  tacc += stc[nl][lane];
#pragma unroll
  for (int v = 0; v < NV; ++v) {
    int cb = h * DOUT + c0 + 4 * v;
    acc[v].x += sacc[nl][cb + 0];
    acc[v].y += sacc[nl][cb + 1];
    acc[v].z += sacc[nl][cb + 2];
    acc[v].w += sacc[nl][cb + 3];
  }

  // epilogue: normalize, add (sum attn*ea)@we, head mean, skip, ELU
  float invl = (lsum > 0.f) ? 1.f / lsum : 0.f;
  float tn = tacc * invl;
  float4 val[NV];
#pragma unroll
  for (int v = 0; v < NV; ++v) {
    val[v].x = acc[v].x * invl; val[v].y = acc[v].y * invl;
    val[v].z = acc[v].z * invl; val[v].w = acc[v].w * invl;
  }
#pragma unroll
  for (int d = 0; d < 16; ++d) {
    float td = __shfl(tn, (lane & 48) | d);
    const float* wb = we + d * HD + h * DOUT + c0;
#pragma unroll
    for (int v = 0; v < NV; ++v) {
      float4 w4 = *reinterpret_cast<const float4*>(wb + 4 * v);
      val[v].x += td * w4.x; val[v].y += td * w4.y;
      val[v].z += td * w4.z; val[v].w += td * w4.w;
    }
  }
#pragma unroll
  for (int v = 0; v < NV; ++v) {
    val[v].x += __shfl_xor(val[v].x, 16); val[v].x += __shfl_xor(val[v].x, 32);
    val[v].y += __shfl_xor(val[v].y, 16); val[v].y += __shfl_xor(val[v].y, 32);
    val[v].z += __shfl_xor(val[v].z, 16); val[v].z += __shfl_xor(val[v].z, 32);
    val[v].w += __shfl_xor(val[v].w, 16); val[v].w += __shfl_xor(val[v].w, 32);
  }
  if (h == 0) {
    KWT sw = *reinterpret_cast<const KWT*>(base + HD + 64 + c0);
    float4 sk[NV];
    cvt_kv(sw, sk);
#pragma unroll
    for (int v = 0; v < NV; ++v) {
      float4 o;
      o.x = 0.25f * val[v].x + sk[v].x;
      o.y = 0.25f * val[v].y + sk[v].y;
      o.z = 0.25f * val[v].z + sk[v].z;
      o.w = 0.25f * val[v].w + sk[v].w;
      o.x = (o.x > 0.f) ? o.x : expm1f(o.x);
      o.y = (o.y > 0.f) ? o.y : expm1f(o.y);
      o.z = (o.z > 0.f) ? o.z : expm1f(o.z);
      o.w = (o.w > 0.f) ? o.w : expm1f(o.w);
      *reinterpret_cast<float4*>(out + (size_t)n * DOUT + c0 + 4 * v) = o;
      __half2* o16 = reinterpret_cast<__half2*>(out16 + (size_t)n * DOUT + c0 + 4 * v);
      o16[0] = __floats2half2_rn(o.x, o.y);
      o16[1] = __floats2half2_rn(o.z, o.w);
    }
  }
}

// ---------------------------------------------------------------------------
// Global mean pool (batch sorted -> contiguous per-graph ranges)
// ---------------------------------------------------------------------------
__device__ inline int lower_bound(const int* b, int n, int v) {
  int lo = 0, hi = n;
  while (lo < hi) {
    int mid = (lo + hi) >> 1;
    if (b[mid] < v) lo = mid + 1; else hi = mid;
  }
  return lo;
}

__global__ __launch_bounds__(256) void pool_all(const float* __restrict__ h,
                                                const int* __restrict__ batch,
                                                float* __restrict__ out) {
  const int g = blockIdx.x;
  const int start = lower_bound(batch, N_NODES, g);
  const int end = lower_bound(batch, N_NODES, g + 1);
  const int c = threadIdx.x & 63, j = threadIdx.x >> 6;
  float s = 0.f;
  for (int n = start + j; n < end; n += 4) s += h[(size_t)n * 64 + c];
  __shared__ float red[4][64];
  red[j][c] = s;
  __syncthreads();
  if (j == 0) {
    float tot = red[0][c] + red[1][c] + red[2][c] + red[3][c];
    out[g * 64 + c] = tot / (float)max(end - start, 1);
  }
}

// ---------------------------------------------------------------------------
extern "C" void kernel_launch(void* const* d_in, const int* in_sizes, int n_in,
                              void* d_out, int out_size, void* d_ws, size_t ws_size,
                              hipStream_t stream) {
  const float* x = (const float*)d_in[0];
  const int* edge_index = (const int*)d_in[1];
  const float* edge_attr = (const float*)d_in[2];
  const int* batch = (const int*)d_in[3];
  const int* srcp = edge_index;
  const int* dstp = edge_index + N_EDGES;

  const bool dict_order = in_sizes[5] > 1024;
  const float *wq[3], *wk[3], *wv[3], *wep[3], *wsk[3], *bq[3], *bk[3], *bv[3], *bs[3];
  for (int L = 0; L < 3; ++L) {
    int b = 4 + L * 9;
    if (dict_order) {
      wq[L] = (const float*)d_in[b + 0];
      wk[L] = (const float*)d_in[b + 1];
      wv[L] = (const float*)d_in[b + 2];
      wep[L] = (const float*)d_in[b + 3];
      wsk[L] = (const float*)d_in[b + 4];
      bq[L] = (const float*)d_in[b + 5];
      bk[L] = (const float*)d_in[b + 6];
      bv[L] = (const float*)d_in[b + 7];
      bs[L] = (const float*)d_in[b + 8];
    } else {
      wq[L] = (const float*)d_in[b + 0];
      bq[L] = (const float*)d_in[b + 1];
      wk[L] = (const float*)d_in[b + 2];
      bk[L] = (const float*)d_in[b + 3];
      wv[L] = (const float*)d_in[b + 4];
      bv[L] = (const float*)d_in[b + 5];
      wep[L] = (const float*)d_in[b + 6];
      wsk[L] = (const float*)d_in[b + 7];
      bs[L] = (const float*)d_in[b + 8];
    }
  }

  // Workspace carve (bytes).
  char* p = (char*)d_ws;
  __half* qs = (__half*)p;    p += (size_t)N_NODES * 704 * 2;   // Q|G|S f16 (max L2)
  __half* kv = (__half*)p;    p += (size_t)N_NODES * 1024 * 2;  // K|V f16 interleaved
  float* h1 = (float*)p;      p += (size_t)N_NODES * 64 * 4;
  float* h2 = (float*)p;      p += (size_t)N_NODES * 128 * 4;
  __half* x16 = (__half*)p;   p += (size_t)N_NODES * 128 * 2;
  __half* h16 = (__half*)p;   p += (size_t)N_NODES * 128 * 2;
  __half* W1 = (__half*)p;    p += 128 * 896 * 2;
  __half* W2 = (__half*)p;    p += 64 * 1728 * 2;
  __half* W3 = (__half*)p;    p += 128 * 896 * 2;
  float* b1 = (float*)p;      p += 896 * 4;
  float* b2 = (float*)p;      p += 1728 * 4;
  float* b3 = (float*)p;      p += 896 * 4;
  float* csr_ea = (float*)p;  p += (size_t)N_EDGES * 16 * 4;
  int* cnt = (int*)p;         p += N_NODES * 4;
  int* cursor = (int*)p;      p += N_NODES * 4;
  int* offs = (int*)p;        p += (N_NODES + 1) * 4;
  int* csr_src = (int*)p;     p += N_EDGES * 4;

  // ---- pack weights (f16 frag order, fused G cols) + x->f16 (1 launch) ----
  pack_all<<<1024, 256, 0, stream>>>(
      wq[0], wk[0], wv[0], wsk[0], wep[0], bq[0], bk[0], bv[0], bs[0],
      wq[1], wk[1], wv[1], wsk[1], wep[1], bq[1], bk[1], bv[1], bs[1],
      wq[2], wk[2], wv[2], wsk[2], wep[2], bq[2], bk[2], bv[2], bs[2],
      W1, b1, W2, b2, W3, b3, x, x16);

  // ---- CSR build over dst ----
  hipMemsetAsync(cnt, 0, 2 * N_NODES * sizeof(int), stream);  // cnt + cursor
  count_dst<<<(N_EDGES + 255) / 256, 256, 0, stream>>>(dstp, cnt);
  scan_offs<<<1, 1024, 0, stream>>>(cnt, offs);
  scatter_csr<<<(N_EDGES + 255) / 256, 256, 0, stream>>>(srcp, dstp, edge_attr,
                                                         offs, cursor, csr_src, csr_ea);

  const int MT = (N_NODES + 63) / 64;
  // ---- layer 1: K=128, HD=256, DOUT=64 ----
  gemm_mfma<128, 256, 64><<<dim3(896 / 64, MT), 256, 0, stream>>>(x16, W1, b1, qs,
                                                                  kv, N_NODES);
  edge_attn<64><<<N_NODES / 2, 256, 0, stream>>>(qs, kv, wep[0], csr_src, csr_ea,
                                                 offs, h1, h16);
  // ---- layer 2: K=64, HD=512, DOUT=128 ----
  gemm_mfma<64, 512, 128><<<dim3(1728 / 64, MT), 256, 0, stream>>>(h16, W2, b2, qs,
                                                                   kv, N_NODES);
  edge_attn<128><<<N_NODES / 2, 256, 0, stream>>>(qs, kv, wep[1], csr_src, csr_ea,
                                                  offs, h2, h16);
  // ---- layer 3: K=128, HD=256, DOUT=64 ----
  gemm_mfma<128, 256, 64><<<dim3(896 / 64, MT), 256, 0, stream>>>(h16, W3, b3, qs,
                                                                  kv, N_NODES);
  edge_attn<64><<<N_NODES / 2, 256, 0, stream>>>(qs, kv, wep[2], csr_src, csr_ea,
                                                 offs, h1, x16 /*scratch*/);

  // ---- global mean pool ----
  pool_all<<<N_GRAPHS, 256, 0, stream>>>(h1, batch, (float*)d_out);
}

// Round 8
// 364.343 us; speedup vs baseline: 1.0272x; 1.0272x over previous
//
#include <hip/hip_runtime.h>
#include <hip/hip_fp16.h>
#include <math.h>

#define N_NODES 10000
#define N_EDGES 160000
#define N_GRAPHS 64

using half8 = __attribute__((ext_vector_type(8))) _Float16;
using floatx4 = __attribute__((ext_vector_type(4))) float;

template <int NV> struct KW;
template <> struct KW<1> { using T = uint2; };
template <> struct KW<2> { using T = uint4; };

__device__ inline void cvt_kv(const uint2& w, float4* dst) {
  float2 a = __half22float2(*reinterpret_cast<const __half2*>(&w.x));
  float2 b = __half22float2(*reinterpret_cast<const __half2*>(&w.y));
  dst[0] = make_float4(a.x, a.y, b.x, b.y);
}
__device__ inline void cvt_kv(const uint4& w, float4* dst) {
  float2 a = __half22float2(*reinterpret_cast<const __half2*>(&w.x));
  float2 b = __half22float2(*reinterpret_cast<const __half2*>(&w.y));
  float2 c = __half22float2(*reinterpret_cast<const __half2*>(&w.z));
  float2 d = __half22float2(*reinterpret_cast<const __half2*>(&w.w));
  dst[0] = make_float4(a.x, a.y, b.x, b.y);
  dst[1] = make_float4(c.x, c.y, d.x, d.y);
}

// ---------------------------------------------------------------------------
// MFMA GEMM: [Q|G|K|V|S] = A[M,K]_f16 @ Wp_f16 + bias_f32.
// Epilogue stages the 64x64 f16 tile in LDS, then vector-stores:
//   Q/G/S cols -> QS row-major; K/V cols -> KV INTERLEAVED lane-block layout.
// ---------------------------------------------------------------------------
template <int K, int HD, int DOUT>
__global__ __launch_bounds__(256) void gemm_mfma(
    const __half* __restrict__ A, const __half* __restrict__ Wp,
    const float* __restrict__ bias, __half* __restrict__ QS,
    __half* __restrict__ KV, int M) {
  constexpr int QSS = HD + 64 + DOUT;
  constexpr int KVS = 2 * HD;
  constexpr int NV = DOUT / 64;
  constexpr int KS = K / 32;
  __shared__ __half st[64][72];
  const int tid = threadIdx.x;
  const int wave = tid >> 6, lane = tid & 63;
  const int quad = lane >> 4, n16 = lane & 15;
  const int row0 = blockIdx.y * 64;
  const int col0 = blockIdx.x * 64;
  const int nblk0 = blockIdx.x * 4;

  const int arow = min(row0 + wave * 16 + n16, M - 1);
  half8 afrag[KS];
#pragma unroll
  for (int s = 0; s < KS; ++s)
    afrag[s] = *reinterpret_cast<const half8*>(A + (size_t)arow * K + s * 32 + quad * 8);

  floatx4 acc[4];
#pragma unroll
  for (int t = 0; t < 4; ++t) {
    acc[t] = (floatx4){0.f, 0.f, 0.f, 0.f};
#pragma unroll
    for (int s = 0; s < KS; ++s) {
      half8 bf = *reinterpret_cast<const half8*>(
          Wp + (((size_t)(nblk0 + t) * KS + s) * 64 + lane) * 8);
      acc[t] = __builtin_amdgcn_mfma_f32_16x16x32_f16(afrag[s], bf, acc[t], 0, 0, 0);
    }
  }

#pragma unroll
  for (int t = 0; t < 4; ++t) {
    float bv = bias[col0 + t * 16 + n16];
#pragma unroll
    for (int r = 0; r < 4; ++r)
      st[wave * 16 + quad * 4 + r][t * 16 + n16] = __float2half(acc[t][r] + bv);
  }
  __syncthreads();

  if (col0 < HD + 64 || col0 >= 3 * HD + 64) {
    const int qcol = (col0 < HD + 64) ? col0 : (HD + 64 + (col0 - 3 * HD - 64));
    for (int c = tid; c < 512; c += 256) {
      int r = c >> 3, seg = c & 7;
      int row = row0 + r;
      if (row < M)
        *reinterpret_cast<uint4*>(QS + (size_t)row * QSS + qcol + seg * 8) =
            *reinterpret_cast<const uint4*>(&st[r][seg * 8]);
    }
  } else {
    constexpr int G = 4 * NV;       // halfs per lane-chunk
    constexpr int NG = 64 / G;      // chunks per 64-col block
    const int ckv0 = col0 - (HD + 64);  // in [0, 2*HD), block fully K or V
    for (int c = tid; c < 64 * NG; c += 256) {
      int r = c / NG, gl = c % NG;
      int row = row0 + r;
      if (row >= M) continue;
      int ckv = ckv0 + gl * G;
      int off;
      if (ckv < HD) off = (ckv / G) * (2 * G);
      else          off = ((ckv - HD) / G) * (2 * G) + G;
      if (NV == 1)
        *reinterpret_cast<uint2*>(KV + (size_t)row * KVS + off) =
            *reinterpret_cast<const uint2*>(&st[r][gl * G]);
      else
        *reinterpret_cast<uint4*>(KV + (size_t)row * KVS + off) =
            *reinterpret_cast<const uint4*>(&st[r][gl * G]);
    }
  }
}

// ---------------------------------------------------------------------------
// Pack weights into B-fragment order (f16), with fused G columns:
//   Wg[k, h*16+d] = SCALE * sum_c wq[k,h*DOUT+c] * we[d,h*DOUT+c]
// Q columns pre-scaled. Tail range converts x -> f16.
// ---------------------------------------------------------------------------
__device__ inline void pack_layer(int i, int K, int HD, int DOUT, float scale,
                                  const float* wq, const float* wk,
                                  const float* wv, const float* wsk,
                                  const float* we, const float* bq,
                                  const float* bk, const float* bv,
                                  const float* bs, __half* Wp, float* bcat) {
  const int W = 3 * HD + DOUT + 64;
  const int KS = K / 32;
  if (i < K * W) {
    int j = i & 7, lane = (i >> 3) & 63, fs = i >> 9;
    int nblk = fs / KS, s = fs - nblk * KS;
    int quad = lane >> 4, n = lane & 15;
    int k = s * 32 + quad * 8 + j, c = nblk * 16 + n;
    float v;
    if (c < HD) {
      v = wq[k * HD + c] * scale;
    } else if (c < HD + 64) {
      int gi = c - HD, hh = gi >> 4, d = gi & 15;
      float a = 0.f;
      for (int cc = 0; cc < DOUT; ++cc)
        a += wq[k * HD + hh * DOUT + cc] * we[d * HD + hh * DOUT + cc];
      v = a * scale;
    } else if (c < 2 * HD + 64) {
      v = wk[k * HD + (c - HD - 64)];
    } else if (c < 3 * HD + 64) {
      v = wv[k * HD + (c - 2 * HD - 64)];
    } else {
      v = wsk[k * DOUT + (c - 3 * HD - 64)];
    }
    Wp[i] = __float2half(v);
  } else {
    int c = i - K * W;
    float v;
    if (c < HD) {
      v = bq[c] * scale;
    } else if (c < HD + 64) {
      int gi = c - HD, hh = gi >> 4, d = gi & 15;
      float a = 0.f;
      for (int cc = 0; cc < DOUT; ++cc)
        a += bq[hh * DOUT + cc] * we[d * HD + hh * DOUT + cc];
      v = a * scale;
    } else if (c < 2 * HD + 64) {
      v = bk[c - HD - 64];
    } else if (c < 3 * HD + 64) {
      v = bv[c - 2 * HD - 64];
    } else {
      v = bs[c - 3 * HD - 64];
    }
    bcat[c] = v;
  }
}

#define T1 115584            // 128*896 + 896
#define T2 227904            // T1 + 64*1728 + 1728
#define T3 343488            // T2 + 128*896 + 896
#define TCONV (N_NODES * 32) // x float4 count
#define TTOT (T3 + TCONV)

__global__ void pack_all(
    const float* wq1, const float* wk1, const float* wv1, const float* ws1,
    const float* we1, const float* bq1, const float* bk1, const float* bv1,
    const float* bs1,
    const float* wq2, const float* wk2, const float* wv2, const float* ws2,
    const float* we2, const float* bq2, const float* bk2, const float* bv2,
    const float* bs2,
    const float* wq3, const float* wk3, const float* wv3, const float* ws3,
    const float* we3, const float* bq3, const float* bk3, const float* bv3,
    const float* bs3,
    __half* W1, float* b1, __half* W2, float* b2, __half* W3, float* b3,
    const float* x, __half* x16) {
  const float SC1 = 0.125f, SC2 = 0.08838834764831845f;
  for (int i = blockIdx.x * blockDim.x + threadIdx.x; i < TTOT;
       i += gridDim.x * blockDim.x) {
    if (i < T1)
      pack_layer(i, 128, 256, 64, SC1, wq1, wk1, wv1, ws1, we1, bq1, bk1, bv1, bs1, W1, b1);
    else if (i < T2)
      pack_layer(i - T1, 64, 512, 128, SC2, wq2, wk2, wv2, ws2, we2, bq2, bk2, bv2, bs2, W2, b2);
    else if (i < T3)
      pack_layer(i - T2, 128, 256, 64, SC1, wq3, wk3, wv3, ws3, we3, bq3, bk3, bv3, bs3, W3, b3);
    else {
      int k = i - T3;
      float4 v = reinterpret_cast<const float4*>(x)[k];
      __half2* o = reinterpret_cast<__half2*>(x16) + 2 * k;
      o[0] = __floats2half2_rn(v.x, v.y);
      o[1] = __floats2half2_rn(v.z, v.w);
    }
  }
}

// ---------------------------------------------------------------------------
// CSR build over dst
// ---------------------------------------------------------------------------
__global__ void count_dst(const int* __restrict__ dst, int* __restrict__ cnt) {
  int e = blockIdx.x * blockDim.x + threadIdx.x;
  if (e < N_EDGES) atomicAdd(&cnt[dst[e]], 1);
}

__global__ __launch_bounds__(1024) void scan_offs(const int* __restrict__ cnt,
                                                  int* __restrict__ offs) {
  __shared__ int part[1024];
  const int t = threadIdx.x;
  const int chunk = (N_NODES + 1023) / 1024;
  const int b = t * chunk;
  const int e = min(N_NODES, b + chunk);
  int s = 0;
  for (int i = b; i < e; ++i) s += cnt[i];
  part[t] = s;
  __syncthreads();
  for (int off = 1; off < 1024; off <<= 1) {
    int v = (t >= off) ? part[t - off] : 0;
    __syncthreads();
    part[t] += v;
    __syncthreads();
  }
  int pre = (t == 0) ? 0 : part[t - 1];
  for (int i = b; i < e; ++i) { offs[i] = pre; pre += cnt[i]; }
  if (t == 0) offs[N_NODES] = part[1023];
}

__global__ void scatter_csr(const int* __restrict__ src, const int* __restrict__ dst,
                            const float* __restrict__ edge_attr,
                            const int* __restrict__ offs, int* __restrict__ cursor,
                            int* __restrict__ csr_src, float* __restrict__ csr_ea) {
  int e = blockIdx.x * blockDim.x + threadIdx.x;
  if (e < N_EDGES) {
    int d = dst[e];
    int pos = offs[d] + atomicAdd(&cursor[d], 1);
    csr_src[pos] = src[e];
    float4* o4 = reinterpret_cast<float4*>(csr_ea + (size_t)pos * 16);
    const float4* s4 = reinterpret_cast<const float4*>(edge_attr + (size_t)e * 16);
    o4[0] = s4[0]; o4[1] = s4[1]; o4[2] = s4[2]; o4[3] = s4[3];
  }
}

// ---------------------------------------------------------------------------
// Fused edge kernel: ONE WAVE PER NODE (R6 structure). Head-local lanes,
// folded edge algebra, fp16 QS / interleaved KV, no-max softmax.
// New: per-64-edge-chunk coalesced src preload (+shfl addressing), coalesced
// ea preload (+shfl broadcast), 8-edge groups for NV=1, ping-pong pipeline.
// ---------------------------------------------------------------------------
template <int DOUT>
__global__ __launch_bounds__(256) void edge_attn(
    const __half* __restrict__ QS, const __half* __restrict__ KV,
    const float* __restrict__ we, const int* __restrict__ csr_src,
    const float* __restrict__ csr_ea, const int* __restrict__ offs,
    float* __restrict__ out, __half* __restrict__ out16) {
  constexpr int HD = 4 * DOUT;
  constexpr int QSS = HD + 64 + DOUT;
  constexpr int KVS = 2 * HD;
  constexpr int NV = DOUT / 64;
  constexpr int EPG = (NV == 1) ? 8 : 4;  // edges per pipeline group
  constexpr int NEA = EPG / 4;            // 256B ea loads per group
  constexpr int NVR = (NV == 2) ? EPG : 1;
  using KWT = typename KW<NV>::T;

  const int lane = threadIdx.x & 63;
  const int h = lane >> 4, t16 = lane & 15;
  const int n = blockIdx.x * 4 + (threadIdx.x >> 6);  // N_NODES % 4 == 0
  const int c0 = t16 * 4 * NV;
  const int bofs = (h * 16 + t16) * 8 * NV;  // interleaved KV lane offset

  const __half* base = QS + (size_t)n * QSS;
  float4 q[NV], acc[NV];
  {
    KWT qw = *reinterpret_cast<const KWT*>(base + h * DOUT + c0);
    cvt_kv(qw, q);
  }
#pragma unroll
  for (int v = 0; v < NV; ++v) acc[v] = make_float4(0.f, 0.f, 0.f, 0.f);
  const float g = __half2float(base[HD + h * 16 + t16]);  // pre-scaled G

  float lsum = 0.f, tacc = 0.f;

  const int s0 = offs[n], s1 = offs[n + 1];
  const int deg = s1 - s0;
  const int gend = s0 + (deg & ~(EPG - 1));

  int srcv = 0;
  float eavA[NEA], eavB[NEA];
  uint4 krA[EPG], krB[EPG];
  uint4 vrA[NVR], vrB[NVR];

  auto load_grp = [&](int bi, int rel, float (&eav)[NEA], uint4 (&kr)[EPG],
                      uint4 (&vr)[NVR]) {
#pragma unroll
    for (int u = 0; u < NEA; ++u)
      eav[u] = csr_ea[(size_t)(bi + 4 * u) * 16 + lane];
#pragma unroll
    for (int j = 0; j < EPG; ++j) {
      int sj = __shfl(srcv, rel + j);
      const __half* rb = KV + (size_t)sj * KVS + bofs;
      kr[j] = *reinterpret_cast<const uint4*>(rb);
      if (NV == 2) vr[j % NVR] = *reinterpret_cast<const uint4*>(rb + 8);
    }
  };

  auto compute_grp = [&](float (&eav)[NEA], uint4 (&kr)[EPG], uint4 (&vr)[NVR]) {
    float a[EPG], eat[EPG];
#pragma unroll
    for (int j = 0; j < EPG; ++j) {
      eat[j] = __shfl(eav[j >> 2], ((j & 3) << 4) | t16);
      float4 kk[NV];
      if (NV == 1) {
        uint2 kw = make_uint2(kr[j].x, kr[j].y);
        cvt_kv(kw, kk);
      } else {
        cvt_kv(kr[j], kk);
      }
      float p = eat[j] * g;
#pragma unroll
      for (int v = 0; v < NV; ++v)
        p += q[v].x * kk[v].x + q[v].y * kk[v].y + q[v].z * kk[v].z +
             q[v].w * kk[v].w;
      a[j] = p;
    }
#pragma unroll
    for (int j = 0; j < EPG; ++j) {
      a[j] += __shfl_xor(a[j], 1);
      a[j] += __shfl_xor(a[j], 2);
      a[j] += __shfl_xor(a[j], 4);
      a[j] += __shfl_xor(a[j], 8);
    }
    float p[EPG];
#pragma unroll
    for (int j = 0; j < EPG; ++j) {
      p[j] = __expf(a[j]);
      lsum += p[j];
      tacc += p[j] * eat[j];
    }
#pragma unroll
    for (int j = 0; j < EPG; ++j) {
      float4 vv[NV];
      if (NV == 1) {
        uint2 vw = make_uint2(kr[j].z, kr[j].w);
        cvt_kv(vw, vv);
      } else {
        cvt_kv(vr[j % NVR], vv);
      }
#pragma unroll
      for (int v = 0; v < NV; ++v) {
        acc[v].x += p[j] * vv[v].x;
        acc[v].y += p[j] * vv[v].y;
        acc[v].z += p[j] * vv[v].z;
        acc[v].w += p[j] * vv[v].w;
      }
    }
  };

  for (int cbase = s0; cbase < gend; cbase += 64) {
    const int cend = min(cbase + 64, gend);
    srcv = csr_src[min(cbase + lane, s1 - 1)];
    int ii = cbase;
    load_grp(ii, 0, eavA, krA, vrA);
    for (;;) {
      int nx = ii + EPG;
      if (nx >= cend) { compute_grp(eavA, krA, vrA); break; }
      load_grp(nx, nx - cbase, eavB, krB, vrB);
      compute_grp(eavA, krA, vrA);
      ii = nx; nx = ii + EPG;
      if (nx >= cend) { compute_grp(eavB, krB, vrB); break; }
      load_grp(nx, nx - cbase, eavA, krA, vrA);
      compute_grp(eavB, krB, vrB);
      ii = nx;
    }
  }

  // tail (deg % EPG edges): direct loads
  for (int t = gend; t < s1; ++t) {
    int s = csr_src[t];
    float ea0 = csr_ea[(size_t)t * 16 + t16];
    const __half* rb = KV + (size_t)s * KVS + bofs;
    float4 kk[NV], vv[NV];
    if (NV == 1) {
      uint4 w = *reinterpret_cast<const uint4*>(rb);
      uint2 kw = make_uint2(w.x, w.y), vw = make_uint2(w.z, w.w);
      cvt_kv(kw, kk);
      cvt_kv(vw, vv);
    } else {
      cvt_kv(*reinterpret_cast<const uint4*>(rb), kk);
      cvt_kv(*reinterpret_cast<const uint4*>(rb + 8), vv);
    }
    float a = ea0 * g;
#pragma unroll
    for (int v = 0; v < NV; ++v)
      a += q[v].x * kk[v].x + q[v].y * kk[v].y + q[v].z * kk[v].z + q[v].w * kk[v].w;
    a += __shfl_xor(a, 1);
    a += __shfl_xor(a, 2);
    a += __shfl_xor(a, 4);
    a += __shfl_xor(a, 8);
    float p = __expf(a);
    lsum += p;
    tacc += p * ea0;
#pragma unroll
    for (int v = 0; v < NV; ++v) {
      acc[v].x += p * vv[v].x;
      acc[v].y += p * vv[v].y;
      acc[v].z += p * vv[v].z;
      acc[v].w += p * vv[v].w;
    }
  }

  // epilogue: normalize, add (sum attn*ea)@we, head mean, skip, ELU
  float invl = (lsum > 0.f) ? 1.f / lsum : 0.f;
  float tn = tacc * invl;
  float4 val[NV];
#pragma unroll
  for (int v = 0; v < NV; ++v) {
    val[v].x = acc[v].x * invl; val[v].y = acc[v].y * invl;
    val[v].z = acc[v].z * invl; val[v].w = acc[v].w * invl;
  }
#pragma unroll
  for (int d = 0; d < 16; ++d) {
    float td = __shfl(tn, (lane & 48) | d);
    const float* wb = we + d * HD + h * DOUT + c0;
#pragma unroll
    for (int v = 0; v < NV; ++v) {
      float4 w4 = *reinterpret_cast<const float4*>(wb + 4 * v);
      val[v].x += td * w4.x; val[v].y += td * w4.y;
      val[v].z += td * w4.z; val[v].w += td * w4.w;
    }
  }
#pragma unroll
  for (int v = 0; v < NV; ++v) {
    val[v].x += __shfl_xor(val[v].x, 16); val[v].x += __shfl_xor(val[v].x, 32);
    val[v].y += __shfl_xor(val[v].y, 16); val[v].y += __shfl_xor(val[v].y, 32);
    val[v].z += __shfl_xor(val[v].z, 16); val[v].z += __shfl_xor(val[v].z, 32);
    val[v].w += __shfl_xor(val[v].w, 16); val[v].w += __shfl_xor(val[v].w, 32);
  }
  if (h == 0) {
    KWT sw = *reinterpret_cast<const KWT*>(base + HD + 64 + c0);
    float4 sk[NV];
    cvt_kv(sw, sk);
#pragma unroll
    for (int v = 0; v < NV; ++v) {
      float4 o;
      o.x = 0.25f * val[v].x + sk[v].x;
      o.y = 0.25f * val[v].y + sk[v].y;
      o.z = 0.25f * val[v].z + sk[v].z;
      o.w = 0.25f * val[v].w + sk[v].w;
      o.x = (o.x > 0.f) ? o.x : expm1f(o.x);
      o.y = (o.y > 0.f) ? o.y : expm1f(o.y);
      o.z = (o.z > 0.f) ? o.z : expm1f(o.z);
      o.w = (o.w > 0.f) ? o.w : expm1f(o.w);
      *reinterpret_cast<float4*>(out + (size_t)n * DOUT + c0 + 4 * v) = o;
      __half2* o16 = reinterpret_cast<__half2*>(out16 + (size_t)n * DOUT + c0 + 4 * v);
      o16[0] = __floats2half2_rn(o.x, o.y);
      o16[1] = __floats2half2_rn(o.z, o.w);
    }
  }
}

// ---------------------------------------------------------------------------
// Global mean pool (batch sorted -> contiguous per-graph ranges)
// ---------------------------------------------------------------------------
__device__ inline int lower_bound(const int* b, int n, int v) {
  int lo = 0, hi = n;
  while (lo < hi) {
    int mid = (lo + hi) >> 1;
    if (b[mid] < v) lo = mid + 1; else hi = mid;
  }
  return lo;
}

__global__ __launch_bounds__(256) void pool_all(const float* __restrict__ h,
                                                const int* __restrict__ batch,
                                                float* __restrict__ out) {
  const int g = blockIdx.x;
  const int start = lower_bound(batch, N_NODES, g);
  const int end = lower_bound(batch, N_NODES, g + 1);
  const int c = threadIdx.x & 63, j = threadIdx.x >> 6;
  float s = 0.f;
  for (int n = start + j; n < end; n += 4) s += h[(size_t)n * 64 + c];
  __shared__ float red[4][64];
  red[j][c] = s;
  __syncthreads();
  if (j == 0) {
    float tot = red[0][c] + red[1][c] + red[2][c] + red[3][c];
    out[g * 64 + c] = tot / (float)max(end - start, 1);
  }
}

// ---------------------------------------------------------------------------
extern "C" void kernel_launch(void* const* d_in, const int* in_sizes, int n_in,
                              void* d_out, int out_size, void* d_ws, size_t ws_size,
                              hipStream_t stream) {
  const float* x = (const float*)d_in[0];
  const int* edge_index = (const int*)d_in[1];
  const float* edge_attr = (const float*)d_in[2];
  const int* batch = (const int*)d_in[3];
  const int* srcp = edge_index;
  const int* dstp = edge_index + N_EDGES;

  const bool dict_order = in_sizes[5] > 1024;
  const float *wq[3], *wk[3], *wv[3], *wep[3], *wsk[3], *bq[3], *bk[3], *bv[3], *bs[3];
  for (int L = 0; L < 3; ++L) {
    int b = 4 + L * 9;
    if (dict_order) {
      wq[L] = (const float*)d_in[b + 0];
      wk[L] = (const float*)d_in[b + 1];
      wv[L] = (const float*)d_in[b + 2];
      wep[L] = (const float*)d_in[b + 3];
      wsk[L] = (const float*)d_in[b + 4];
      bq[L] = (const float*)d_in[b + 5];
      bk[L] = (const float*)d_in[b + 6];
      bv[L] = (const float*)d_in[b + 7];
      bs[L] = (const float*)d_in[b + 8];
    } else {
      wq[L] = (const float*)d_in[b + 0];
      bq[L] = (const float*)d_in[b + 1];
      wk[L] = (const float*)d_in[b + 2];
      bk[L] = (const float*)d_in[b + 3];
      wv[L] = (const float*)d_in[b + 4];
      bv[L] = (const float*)d_in[b + 5];
      wep[L] = (const float*)d_in[b + 6];
      wsk[L] = (const float*)d_in[b + 7];
      bs[L] = (const float*)d_in[b + 8];
    }
  }

  // Workspace carve (bytes).
  char* p = (char*)d_ws;
  __half* qs = (__half*)p;    p += (size_t)N_NODES * 704 * 2;   // Q|G|S f16 (max L2)
  __half* kv = (__half*)p;    p += (size_t)N_NODES * 1024 * 2;  // K|V f16 interleaved
  float* h1 = (float*)p;      p += (size_t)N_NODES * 64 * 4;
  float* h2 = (float*)p;      p += (size_t)N_NODES * 128 * 4;
  __half* x16 = (__half*)p;   p += (size_t)N_NODES * 128 * 2;
  __half* h16 = (__half*)p;   p += (size_t)N_NODES * 128 * 2;
  __half* W1 = (__half*)p;    p += 128 * 896 * 2;
  __half* W2 = (__half*)p;    p += 64 * 1728 * 2;
  __half* W3 = (__half*)p;    p += 128 * 896 * 2;
  float* b1 = (float*)p;      p += 896 * 4;
  float* b2 = (float*)p;      p += 1728 * 4;
  float* b3 = (float*)p;      p += 896 * 4;
  float* csr_ea = (float*)p;  p += (size_t)N_EDGES * 16 * 4;
  int* cnt = (int*)p;         p += N_NODES * 4;
  int* cursor = (int*)p;      p += N_NODES * 4;
  int* offs = (int*)p;        p += (N_NODES + 1) * 4;
  int* csr_src = (int*)p;     p += (N_EDGES + 64) * 4;  // +64 pad for lane over-read

  // ---- pack weights (f16 frag order, fused G cols) + x->f16 (1 launch) ----
  pack_all<<<1024, 256, 0, stream>>>(
      wq[0], wk[0], wv[0], wsk[0], wep[0], bq[0], bk[0], bv[0], bs[0],
      wq[1], wk[1], wv[1], wsk[1], wep[1], bq[1], bk[1], bv[1], bs[1],
      wq[2], wk[2], wv[2], wsk[2], wep[2], bq[2], bk[2], bv[2], bs[2],
      W1, b1, W2, b2, W3, b3, x, x16);

  // ---- CSR build over dst ----
  hipMemsetAsync(cnt, 0, 2 * N_NODES * sizeof(int), stream);  // cnt + cursor
  count_dst<<<(N_EDGES + 255) / 256, 256, 0, stream>>>(dstp, cnt);
  scan_offs<<<1, 1024, 0, stream>>>(cnt, offs);
  scatter_csr<<<(N_EDGES + 255) / 256, 256, 0, stream>>>(srcp, dstp, edge_attr,
                                                         offs, cursor, csr_src, csr_ea);

  const int MT = (N_NODES + 63) / 64;
  // ---- layer 1: K=128, HD=256, DOUT=64 ----
  gemm_mfma<128, 256, 64><<<dim3(896 / 64, MT), 256, 0, stream>>>(x16, W1, b1, qs,
                                                                  kv, N_NODES);
  edge_attn<64><<<N_NODES / 4, 256, 0, stream>>>(qs, kv, wep[0], csr_src, csr_ea,
                                                 offs, h1, h16);
  // ---- layer 2: K=64, HD=512, DOUT=128 ----
  gemm_mfma<64, 512, 128><<<dim3(1728 / 64, MT), 256, 0, stream>>>(h16, W2, b2, qs,
                                                                   kv, N_NODES);
  edge_attn<128><<<N_NODES / 4, 256, 0, stream>>>(qs, kv, wep[1], csr_src, csr_ea,
                                                  offs, h2, h16);
  // ---- layer 3: K=128, HD=256, DOUT=64 ----
  gemm_mfma<128, 256, 64><<<dim3(896 / 64, MT), 256, 0, stream>>>(h16, W3, b3, qs,
                                                                  kv, N_NODES);
  edge_attn<64><<<N_NODES / 4, 256, 0, stream>>>(qs, kv, wep[2], csr_src, csr_ea,
                                                 offs, h1, x16 /*scratch*/);

  // ---- global mean pool ----
  pool_all<<<N_GRAPHS, 256, 0, stream>>>(h1, batch, (float*)d_out);
}

// Round 9
// 356.670 us; speedup vs baseline: 1.0493x; 1.0215x over previous
//
#include <hip/hip_runtime.h>
#include <hip/hip_fp16.h>
#include <math.h>

#define N_NODES 10000
#define N_EDGES 160000
#define N_GRAPHS 64

using half8 = __attribute__((ext_vector_type(8))) _Float16;
using floatx4 = __attribute__((ext_vector_type(4))) float;

// raw f16 fragment word: 4 halfs (NV=1) or 8 halfs (NV=2)
template <int NV> struct KW;
template <> struct KW<1> { using T = uint2; };
template <> struct KW<2> { using T = uint4; };

__device__ inline void cvt_kv(const uint2& w, float4* dst) {
  float2 a = __half22float2(*reinterpret_cast<const __half2*>(&w.x));
  float2 b = __half22float2(*reinterpret_cast<const __half2*>(&w.y));
  dst[0] = make_float4(a.x, a.y, b.x, b.y);
}
__device__ inline void cvt_kv(const uint4& w, float4* dst) {
  float2 a = __half22float2(*reinterpret_cast<const __half2*>(&w.x));
  float2 b = __half22float2(*reinterpret_cast<const __half2*>(&w.y));
  float2 c = __half22float2(*reinterpret_cast<const __half2*>(&w.z));
  float2 d = __half22float2(*reinterpret_cast<const __half2*>(&w.w));
  dst[0] = make_float4(a.x, a.y, b.x, b.y);
  dst[1] = make_float4(c.x, c.y, d.x, d.y);
}

// ---------------------------------------------------------------------------
// MFMA GEMM: [Q|G|K|V|S] = A[M,K]_f16 @ Wp_f16 + bias_f32. No LDS.
// Output split (all f16): c<HD+64 -> QS (Q pre-scaled + G), c<3HD+64 -> KV,
// else -> QS skip columns.   (exact round-6 version — measured best)
// ---------------------------------------------------------------------------
template <int K, int HD, int DOUT>
__global__ __launch_bounds__(256) void gemm_mfma(
    const __half* __restrict__ A, const __half* __restrict__ Wp,
    const float* __restrict__ bias, __half* __restrict__ QS,
    __half* __restrict__ KV, int M) {
  constexpr int QSS = HD + 64 + DOUT;
  constexpr int KS = K / 32;
  const int tid = threadIdx.x;
  const int wave = tid >> 6, lane = tid & 63;
  const int quad = lane >> 4, n16 = lane & 15;
  const int row0 = blockIdx.y * 64 + wave * 16;
  const int col0 = blockIdx.x * 64;
  const int nblk0 = blockIdx.x * 4;

  const int arow = min(row0 + n16, M - 1);
  half8 afrag[KS];
#pragma unroll
  for (int s = 0; s < KS; ++s)
    afrag[s] = *reinterpret_cast<const half8*>(A + (size_t)arow * K + s * 32 + quad * 8);

  floatx4 acc[4];
#pragma unroll
  for (int t = 0; t < 4; ++t) {
    acc[t] = (floatx4){0.f, 0.f, 0.f, 0.f};
#pragma unroll
    for (int s = 0; s < KS; ++s) {
      half8 bf = *reinterpret_cast<const half8*>(
          Wp + (((size_t)(nblk0 + t) * KS + s) * 64 + lane) * 8);
      acc[t] = __builtin_amdgcn_mfma_f32_16x16x32_f16(afrag[s], bf, acc[t], 0, 0, 0);
    }
  }

#pragma unroll
  for (int t = 0; t < 4; ++t) {
    const int c = col0 + t * 16 + n16;
    const float bv = bias[c];
#pragma unroll
    for (int r = 0; r < 4; ++r) {
      int row = row0 + quad * 4 + r;
      if (row < M) {
        __half val = __float2half(acc[t][r] + bv);
        if (c < HD + 64)
          QS[(size_t)row * QSS + c] = val;
        else if (c < 3 * HD + 64)
          KV[(size_t)row * (2 * HD) + (c - HD - 64)] = val;
        else
          QS[(size_t)row * QSS + HD + 64 + (c - 3 * HD - 64)] = val;
      }
    }
  }
}

// ---------------------------------------------------------------------------
// Pack weights into B-fragment order (f16), with fused G columns.
// ---------------------------------------------------------------------------
__device__ inline void pack_layer(int i, int K, int HD, int DOUT, float scale,
                                  const float* wq, const float* wk,
                                  const float* wv, const float* wsk,
                                  const float* we, const float* bq,
                                  const float* bk, const float* bv,
                                  const float* bs, __half* Wp, float* bcat) {
  const int W = 3 * HD + DOUT + 64;
  const int KS = K / 32;
  if (i < K * W) {
    int j = i & 7, lane = (i >> 3) & 63, fs = i >> 9;
    int nblk = fs / KS, s = fs - nblk * KS;
    int quad = lane >> 4, n = lane & 15;
    int k = s * 32 + quad * 8 + j, c = nblk * 16 + n;
    float v;
    if (c < HD) {
      v = wq[k * HD + c] * scale;
    } else if (c < HD + 64) {
      int gi = c - HD, hh = gi >> 4, d = gi & 15;
      float a = 0.f;
      for (int cc = 0; cc < DOUT; ++cc)
        a += wq[k * HD + hh * DOUT + cc] * we[d * HD + hh * DOUT + cc];
      v = a * scale;
    } else if (c < 2 * HD + 64) {
      v = wk[k * HD + (c - HD - 64)];
    } else if (c < 3 * HD + 64) {
      v = wv[k * HD + (c - 2 * HD - 64)];
    } else {
      v = wsk[k * DOUT + (c - 3 * HD - 64)];
    }
    Wp[i] = __float2half(v);
  } else {
    int c = i - K * W;
    float v;
    if (c < HD) {
      v = bq[c] * scale;
    } else if (c < HD + 64) {
      int gi = c - HD, hh = gi >> 4, d = gi & 15;
      float a = 0.f;
      for (int cc = 0; cc < DOUT; ++cc)
        a += bq[hh * DOUT + cc] * we[d * HD + hh * DOUT + cc];
      v = a * scale;
    } else if (c < 2 * HD + 64) {
      v = bk[c - HD - 64];
    } else if (c < 3 * HD + 64) {
      v = bv[c - 2 * HD - 64];
    } else {
      v = bs[c - 3 * HD - 64];
    }
    bcat[c] = v;
  }
}

#define T1 115584            // 128*896 + 896
#define T2 227904            // T1 + 64*1728 + 1728
#define T3 343488            // T2 + 128*896 + 896
#define TCONV (N_NODES * 32) // x float4 count
#define TTOT (T3 + TCONV)

__global__ void pack_all(
    const float* wq1, const float* wk1, const float* wv1, const float* ws1,
    const float* we1, const float* bq1, const float* bk1, const float* bv1,
    const float* bs1,
    const float* wq2, const float* wk2, const float* wv2, const float* ws2,
    const float* we2, const float* bq2, const float* bk2, const float* bv2,
    const float* bs2,
    const float* wq3, const float* wk3, const float* wv3, const float* ws3,
    const float* we3, const float* bq3, const float* bk3, const float* bv3,
    const float* bs3,
    __half* W1, float* b1, __half* W2, float* b2, __half* W3, float* b3,
    const float* x, __half* x16) {
  const float SC1 = 0.125f, SC2 = 0.08838834764831845f;
  for (int i = blockIdx.x * blockDim.x + threadIdx.x; i < TTOT;
       i += gridDim.x * blockDim.x) {
    if (i < T1)
      pack_layer(i, 128, 256, 64, SC1, wq1, wk1, wv1, ws1, we1, bq1, bk1, bv1, bs1, W1, b1);
    else if (i < T2)
      pack_layer(i - T1, 64, 512, 128, SC2, wq2, wk2, wv2, ws2, we2, bq2, bk2, bv2, bs2, W2, b2);
    else if (i < T3)
      pack_layer(i - T2, 128, 256, 64, SC1, wq3, wk3, wv3, ws3, we3, bq3, bk3, bv3, bs3, W3, b3);
    else {
      int k = i - T3;
      float4 v = reinterpret_cast<const float4*>(x)[k];
      __half2* o = reinterpret_cast<__half2*>(x16) + 2 * k;
      o[0] = __floats2half2_rn(v.x, v.y);
      o[1] = __floats2half2_rn(v.z, v.w);
    }
  }
}

// ---------------------------------------------------------------------------
// CSR build over dst
// ---------------------------------------------------------------------------
__global__ void count_dst(const int* __restrict__ dst, int* __restrict__ cnt) {
  int e = blockIdx.x * blockDim.x + threadIdx.x;
  if (e < N_EDGES) atomicAdd(&cnt[dst[e]], 1);
}

// Fused: exclusive scan of degrees -> offs, AND degree-descending counting
// sort of nodes -> perm (schedules heavy nodes first in edge_attn).
__global__ __launch_bounds__(1024) void scan_offs(const int* __restrict__ cnt,
                                                  int* __restrict__ offs,
                                                  int* __restrict__ perm) {
  __shared__ int part[1024];
  __shared__ int hist[256], hstart[256], hcur[256];
  const int t = threadIdx.x;
  const int chunk = (N_NODES + 1023) / 1024;
  const int b = t * chunk;
  const int e = min(N_NODES, b + chunk);
  if (t < 256) { hist[t] = 0; hcur[t] = 0; }
  __syncthreads();
  int s = 0;
  for (int i = b; i < e; ++i) {
    int d = cnt[i];
    s += d;
    atomicAdd(&hist[min(d, 255)], 1);
  }
  part[t] = s;
  __syncthreads();
  for (int off = 1; off < 1024; off <<= 1) {
    int v = (t >= off) ? part[t - off] : 0;
    __syncthreads();
    part[t] += v;
    __syncthreads();
  }
  if (t == 0) {
    int acc = 0;
    for (int bk = 255; bk >= 0; --bk) { hstart[bk] = acc; acc += hist[bk]; }
    offs[N_NODES] = part[1023];
  }
  __syncthreads();
  int pre = (t == 0) ? 0 : part[t - 1];
  for (int i = b; i < e; ++i) {
    offs[i] = pre;
    int d = cnt[i];
    pre += d;
    int bkt = min(d, 255);
    int pos = hstart[bkt] + atomicAdd(&hcur[bkt], 1);
    perm[pos] = i;
  }
}

__global__ void scatter_csr(const int* __restrict__ src, const int* __restrict__ dst,
                            const float* __restrict__ edge_attr,
                            const int* __restrict__ offs, int* __restrict__ cursor,
                            int* __restrict__ csr_src, float* __restrict__ csr_ea) {
  int e = blockIdx.x * blockDim.x + threadIdx.x;
  if (e < N_EDGES) {
    int d = dst[e];
    int pos = offs[d] + atomicAdd(&cursor[d], 1);
    csr_src[pos] = src[e];
    float4* o4 = reinterpret_cast<float4*>(csr_ea + (size_t)pos * 16);
    const float4* s4 = reinterpret_cast<const float4*>(edge_attr + (size_t)e * 16);
    o4[0] = s4[0]; o4[1] = s4[1]; o4[2] = s4[2]; o4[3] = s4[3];
  }
}

// ---------------------------------------------------------------------------
// Fused edge kernel (exact round-6 structure: 1 wave/node, ping-pong 4-edge
// groups, direct loads) + degree-sorted node permutation. W32: write f32 out
// (only needed for the final layer feeding the pool).
// ---------------------------------------------------------------------------
template <int DOUT, bool W32>
__global__ __launch_bounds__(256) void edge_attn(
    const __half* __restrict__ QS, const __half* __restrict__ KV,
    const float* __restrict__ we, const int* __restrict__ csr_src,
    const float* __restrict__ csr_ea, const int* __restrict__ offs,
    const int* __restrict__ perm, float* __restrict__ out,
    __half* __restrict__ out16) {
  constexpr int HD = 4 * DOUT;
  constexpr int QSS = HD + 64 + DOUT;
  constexpr int KVS = 2 * HD;
  constexpr int NV = DOUT / 64;
  using KWT = typename KW<NV>::T;

  const int lane = threadIdx.x & 63;
  const int h = lane >> 4, t16 = lane & 15;
  const int n = perm[blockIdx.x * 4 + (threadIdx.x >> 6)];  // N_NODES % 4 == 0
  const int c0 = t16 * 4 * NV;

  const __half* base = QS + (size_t)n * QSS;
  float4 q[NV], acc[NV];
  {
    KWT qw = *reinterpret_cast<const KWT*>(base + h * DOUT + c0);
    cvt_kv(qw, q);
  }
#pragma unroll
  for (int v = 0; v < NV; ++v) acc[v] = make_float4(0.f, 0.f, 0.f, 0.f);
  const float g = __half2float(base[HD + h * 16 + t16]);  // pre-scaled G

  float lsum = 0.f, tacc = 0.f;

  const int s0 = offs[n], s1 = offs[n + 1];

  int sjA[4], sjB[4];
  float eaA[4], eaB[4];
  KWT krA[4], vrA[4], krB[4], vrB[4];

  auto load_grp = [&](int bi, int (&sj)[4], float (&ea)[4], KWT (&kr)[4],
                      KWT (&vr)[4]) {
#pragma unroll
    for (int j = 0; j < 4; ++j) sj[j] = csr_src[bi + j];
#pragma unroll
    for (int j = 0; j < 4; ++j) ea[j] = csr_ea[(size_t)(bi + j) * 16 + t16];
#pragma unroll
    for (int j = 0; j < 4; ++j) {
      const __half* rb = KV + (size_t)sj[j] * KVS + h * DOUT + c0;
      kr[j] = *reinterpret_cast<const KWT*>(rb);
      vr[j] = *reinterpret_cast<const KWT*>(rb + HD);
    }
  };

  auto compute_grp = [&](float (&ea)[4], KWT (&kr)[4], KWT (&vr)[4]) {
    float a[4];
#pragma unroll
    for (int j = 0; j < 4; ++j) {
      float4 kk[NV];
      cvt_kv(kr[j], kk);
      float p = ea[j] * g;
#pragma unroll
      for (int v = 0; v < NV; ++v)
        p += q[v].x * kk[v].x + q[v].y * kk[v].y + q[v].z * kk[v].z +
             q[v].w * kk[v].w;
      a[j] = p;
    }
#pragma unroll
    for (int j = 0; j < 4; ++j) {
      a[j] += __shfl_xor(a[j], 1);
      a[j] += __shfl_xor(a[j], 2);
      a[j] += __shfl_xor(a[j], 4);
      a[j] += __shfl_xor(a[j], 8);
    }
    float p0 = __expf(a[0]), p1 = __expf(a[1]);
    float p2 = __expf(a[2]), p3 = __expf(a[3]);
    lsum += p0 + p1 + p2 + p3;
    tacc += p0 * ea[0] + p1 * ea[1] + p2 * ea[2] + p3 * ea[3];
    float pj[4] = {p0, p1, p2, p3};
#pragma unroll
    for (int j = 0; j < 4; ++j) {
      float4 vv[NV];
      cvt_kv(vr[j], vv);
#pragma unroll
      for (int v = 0; v < NV; ++v) {
        acc[v].x += pj[j] * vv[v].x;
        acc[v].y += pj[j] * vv[v].y;
        acc[v].z += pj[j] * vv[v].z;
        acc[v].w += pj[j] * vv[v].w;
      }
    }
  };

  int ii = s0;
  const int end_full = s0 + ((s1 - s0) & ~3);
  if (ii < end_full) {
    load_grp(ii, sjA, eaA, krA, vrA);
    for (;;) {
      int nx = ii + 4;
      if (nx >= end_full) { compute_grp(eaA, krA, vrA); ii = nx; break; }
      load_grp(nx, sjB, eaB, krB, vrB);
      compute_grp(eaA, krA, vrA);
      ii = nx; nx = ii + 4;
      if (nx >= end_full) { compute_grp(eaB, krB, vrB); ii = nx; break; }
      load_grp(nx, sjA, eaA, krA, vrA);
      compute_grp(eaB, krB, vrB);
      ii = nx;
    }
  }

  for (; ii < s1; ++ii) {
    int s = csr_src[ii];
    float ea0 = csr_ea[(size_t)ii * 16 + t16];
    const __half* rb = KV + (size_t)s * KVS + h * DOUT + c0;
    KWT kw = *reinterpret_cast<const KWT*>(rb);
    KWT vw = *reinterpret_cast<const KWT*>(rb + HD);
    float4 kk[NV], vv[NV];
    cvt_kv(kw, kk);
    cvt_kv(vw, vv);
    float a = ea0 * g;
#pragma unroll
    for (int v = 0; v < NV; ++v)
      a += q[v].x * kk[v].x + q[v].y * kk[v].y + q[v].z * kk[v].z + q[v].w * kk[v].w;
    a += __shfl_xor(a, 1);
    a += __shfl_xor(a, 2);
    a += __shfl_xor(a, 4);
    a += __shfl_xor(a, 8);
    float p = __expf(a);
    lsum += p;
    tacc += p * ea0;
#pragma unroll
    for (int v = 0; v < NV; ++v) {
      acc[v].x += p * vv[v].x;
      acc[v].y += p * vv[v].y;
      acc[v].z += p * vv[v].z;
      acc[v].w += p * vv[v].w;
    }
  }

  // epilogue: normalize, add (sum attn*ea)@we, head mean, skip, ELU
  float invl = (lsum > 0.f) ? 1.f / lsum : 0.f;
  float tn = tacc * invl;
  float4 val[NV];
#pragma unroll
  for (int v = 0; v < NV; ++v) {
    val[v].x = acc[v].x * invl; val[v].y = acc[v].y * invl;
    val[v].z = acc[v].z * invl; val[v].w = acc[v].w * invl;
  }
#pragma unroll
  for (int d = 0; d < 16; ++d) {
    float td = __shfl(tn, (lane & 48) | d);
    const float* wb = we + d * HD + h * DOUT + c0;
#pragma unroll
    for (int v = 0; v < NV; ++v) {
      float4 w4 = *reinterpret_cast<const float4*>(wb + 4 * v);
      val[v].x += td * w4.x; val[v].y += td * w4.y;
      val[v].z += td * w4.z; val[v].w += td * w4.w;
    }
  }
#pragma unroll
  for (int v = 0; v < NV; ++v) {
    val[v].x += __shfl_xor(val[v].x, 16); val[v].x += __shfl_xor(val[v].x, 32);
    val[v].y += __shfl_xor(val[v].y, 16); val[v].y += __shfl_xor(val[v].y, 32);
    val[v].z += __shfl_xor(val[v].z, 16); val[v].z += __shfl_xor(val[v].z, 32);
    val[v].w += __shfl_xor(val[v].w, 16); val[v].w += __shfl_xor(val[v].w, 32);
  }
  if (h == 0) {
    KWT sw = *reinterpret_cast<const KWT*>(base + HD + 64 + c0);
    float4 sk[NV];
    cvt_kv(sw, sk);
#pragma unroll
    for (int v = 0; v < NV; ++v) {
      float4 o;
      o.x = 0.25f * val[v].x + sk[v].x;
      o.y = 0.25f * val[v].y + sk[v].y;
      o.z = 0.25f * val[v].z + sk[v].z;
      o.w = 0.25f * val[v].w + sk[v].w;
      o.x = (o.x > 0.f) ? o.x : expm1f(o.x);
      o.y = (o.y > 0.f) ? o.y : expm1f(o.y);
      o.z = (o.z > 0.f) ? o.z : expm1f(o.z);
      o.w = (o.w > 0.f) ? o.w : expm1f(o.w);
      if (W32)
        *reinterpret_cast<float4*>(out + (size_t)n * DOUT + c0 + 4 * v) = o;
      __half2* o16 = reinterpret_cast<__half2*>(out16 + (size_t)n * DOUT + c0 + 4 * v);
      o16[0] = __floats2half2_rn(o.x, o.y);
      o16[1] = __floats2half2_rn(o.z, o.w);
    }
  }
}

// ---------------------------------------------------------------------------
// Global mean pool (batch sorted -> contiguous per-graph ranges)
// ---------------------------------------------------------------------------
__device__ inline int lower_bound(const int* b, int n, int v) {
  int lo = 0, hi = n;
  while (lo < hi) {
    int mid = (lo + hi) >> 1;
    if (b[mid] < v) lo = mid + 1; else hi = mid;
  }
  return lo;
}

__global__ __launch_bounds__(256) void pool_all(const float* __restrict__ h,
                                                const int* __restrict__ batch,
                                                float* __restrict__ out) {
  const int g = blockIdx.x;
  const int start = lower_bound(batch, N_NODES, g);
  const int end = lower_bound(batch, N_NODES, g + 1);
  const int c = threadIdx.x & 63, j = threadIdx.x >> 6;
  float s = 0.f;
  for (int n = start + j; n < end; n += 4) s += h[(size_t)n * 64 + c];
  __shared__ float red[4][64];
  red[j][c] = s;
  __syncthreads();
  if (j == 0) {
    float tot = red[0][c] + red[1][c] + red[2][c] + red[3][c];
    out[g * 64 + c] = tot / (float)max(end - start, 1);
  }
}

// ---------------------------------------------------------------------------
extern "C" void kernel_launch(void* const* d_in, const int* in_sizes, int n_in,
                              void* d_out, int out_size, void* d_ws, size_t ws_size,
                              hipStream_t stream) {
  const float* x = (const float*)d_in[0];
  const int* edge_index = (const int*)d_in[1];
  const float* edge_attr = (const float*)d_in[2];
  const int* batch = (const int*)d_in[3];
  const int* srcp = edge_index;
  const int* dstp = edge_index + N_EDGES;

  const bool dict_order = in_sizes[5] > 1024;
  const float *wq[3], *wk[3], *wv[3], *wep[3], *wsk[3], *bq[3], *bk[3], *bv[3], *bs[3];
  for (int L = 0; L < 3; ++L) {
    int b = 4 + L * 9;
    if (dict_order) {
      wq[L] = (const float*)d_in[b + 0];
      wk[L] = (const float*)d_in[b + 1];
      wv[L] = (const float*)d_in[b + 2];
      wep[L] = (const float*)d_in[b + 3];
      wsk[L] = (const float*)d_in[b + 4];
      bq[L] = (const float*)d_in[b + 5];
      bk[L] = (const float*)d_in[b + 6];
      bv[L] = (const float*)d_in[b + 7];
      bs[L] = (const float*)d_in[b + 8];
    } else {
      wq[L] = (const float*)d_in[b + 0];
      bq[L] = (const float*)d_in[b + 1];
      wk[L] = (const float*)d_in[b + 2];
      bk[L] = (const float*)d_in[b + 3];
      wv[L] = (const float*)d_in[b + 4];
      bv[L] = (const float*)d_in[b + 5];
      wep[L] = (const float*)d_in[b + 6];
      wsk[L] = (const float*)d_in[b + 7];
      bs[L] = (const float*)d_in[b + 8];
    }
  }

  // Workspace carve (bytes).
  char* p = (char*)d_ws;
  __half* qs = (__half*)p;    p += (size_t)N_NODES * 704 * 2;   // Q|G|S f16 (max L2)
  __half* kv = (__half*)p;    p += (size_t)N_NODES * 1024 * 2;  // K|V f16 (max L2)
  float* h1 = (float*)p;      p += (size_t)N_NODES * 64 * 4;
  __half* x16 = (__half*)p;   p += (size_t)N_NODES * 128 * 2;
  __half* h16 = (__half*)p;   p += (size_t)N_NODES * 128 * 2;
  __half* W1 = (__half*)p;    p += 128 * 896 * 2;
  __half* W2 = (__half*)p;    p += 64 * 1728 * 2;
  __half* W3 = (__half*)p;    p += 128 * 896 * 2;
  float* b1 = (float*)p;      p += 896 * 4;
  float* b2 = (float*)p;      p += 1728 * 4;
  float* b3 = (float*)p;      p += 896 * 4;
  float* csr_ea = (float*)p;  p += (size_t)N_EDGES * 16 * 4;
  int* cnt = (int*)p;         p += N_NODES * 4;
  int* cursor = (int*)p;      p += N_NODES * 4;
  int* offs = (int*)p;        p += (N_NODES + 1) * 4;
  int* perm = (int*)p;        p += N_NODES * 4;
  int* csr_src = (int*)p;     p += N_EDGES * 4;

  // ---- pack weights (f16 frag order, fused G cols) + x->f16 (1 launch) ----
  pack_all<<<1024, 256, 0, stream>>>(
      wq[0], wk[0], wv[0], wsk[0], wep[0], bq[0], bk[0], bv[0], bs[0],
      wq[1], wk[1], wv[1], wsk[1], wep[1], bq[1], bk[1], bv[1], bs[1],
      wq[2], wk[2], wv[2], wsk[2], wep[2], bq[2], bk[2], bv[2], bs[2],
      W1, b1, W2, b2, W3, b3, x, x16);

  // ---- CSR build over dst + degree-sorted scheduling permutation ----
  hipMemsetAsync(cnt, 0, 2 * N_NODES * sizeof(int), stream);  // cnt + cursor
  count_dst<<<(N_EDGES + 255) / 256, 256, 0, stream>>>(dstp, cnt);
  scan_offs<<<1, 1024, 0, stream>>>(cnt, offs, perm);
  scatter_csr<<<(N_EDGES + 255) / 256, 256, 0, stream>>>(srcp, dstp, edge_attr,
                                                         offs, cursor, csr_src, csr_ea);

  const int MT = (N_NODES + 63) / 64;
  // ---- layer 1: K=128, HD=256, DOUT=64 ----
  gemm_mfma<128, 256, 64><<<dim3(896 / 64, MT), 256, 0, stream>>>(x16, W1, b1, qs,
                                                                  kv, N_NODES);
  edge_attn<64, false><<<N_NODES / 4, 256, 0, stream>>>(qs, kv, wep[0], csr_src,
                                                        csr_ea, offs, perm, h1, h16);
  // ---- layer 2: K=64, HD=512, DOUT=128 ----
  gemm_mfma<64, 512, 128><<<dim3(1728 / 64, MT), 256, 0, stream>>>(h16, W2, b2, qs,
                                                                   kv, N_NODES);
  edge_attn<128, false><<<N_NODES / 4, 256, 0, stream>>>(qs, kv, wep[1], csr_src,
                                                         csr_ea, offs, perm, h1, h16);
  // ---- layer 3: K=128, HD=256, DOUT=64 ----
  gemm_mfma<128, 256, 64><<<dim3(896 / 64, MT), 256, 0, stream>>>(h16, W3, b3, qs,
                                                                  kv, N_NODES);
  edge_attn<64, true><<<N_NODES / 4, 256, 0, stream>>>(qs, kv, wep[2], csr_src,
                                                       csr_ea, offs, perm, h1, x16);

  // ---- global mean pool ----
  pool_all<<<N_GRAPHS, 256, 0, stream>>>(h1, batch, (float*)d_out);
}

// Round 10
// 334.665 us; speedup vs baseline: 1.1183x; 1.0658x over previous
//
#include <hip/hip_runtime.h>
#include <hip/hip_fp16.h>
#include <math.h>

#define N_NODES 10000
#define N_EDGES 160000
#define N_GRAPHS 64

using half8 = __attribute__((ext_vector_type(8))) _Float16;
using floatx4 = __attribute__((ext_vector_type(4))) float;

// raw f16 fragment word: 4 halfs (NV=1) or 8 halfs (NV=2)
template <int NV> struct KW;
template <> struct KW<1> { using T = uint2; };
template <> struct KW<2> { using T = uint4; };

__device__ inline void cvt_kv(const uint2& w, float4* dst) {
  float2 a = __half22float2(*reinterpret_cast<const __half2*>(&w.x));
  float2 b = __half22float2(*reinterpret_cast<const __half2*>(&w.y));
  dst[0] = make_float4(a.x, a.y, b.x, b.y);
}
__device__ inline void cvt_kv(const uint4& w, float4* dst) {
  float2 a = __half22float2(*reinterpret_cast<const __half2*>(&w.x));
  float2 b = __half22float2(*reinterpret_cast<const __half2*>(&w.y));
  float2 c = __half22float2(*reinterpret_cast<const __half2*>(&w.z));
  float2 d = __half22float2(*reinterpret_cast<const __half2*>(&w.w));
  dst[0] = make_float4(a.x, a.y, b.x, b.y);
  dst[1] = make_float4(c.x, c.y, d.x, d.y);
}

// ---------------------------------------------------------------------------
// MFMA GEMM: [Q|G|K|V|S] = A[M,K]_f16 @ Wp_f16 + bias_f32.
// Epilogue stages the 64x64 f16 tile in LDS, then uint4 vector-stores.
// Each 64-col block lies entirely in one output region (all boundaries are
// multiples of 64), so the store target is block-uniform.
// ---------------------------------------------------------------------------
template <int K, int HD, int DOUT>
__global__ __launch_bounds__(256) void gemm_mfma(
    const __half* __restrict__ A, const __half* __restrict__ Wp,
    const float* __restrict__ bias, __half* __restrict__ QS,
    __half* __restrict__ KV, int M) {
  constexpr int QSS = HD + 64 + DOUT;
  constexpr int KVS = 2 * HD;
  constexpr int KS = K / 32;
  __shared__ __half st[64][72];
  const int tid = threadIdx.x;
  const int wave = tid >> 6, lane = tid & 63;
  const int quad = lane >> 4, n16 = lane & 15;
  const int row0 = blockIdx.y * 64;
  const int col0 = blockIdx.x * 64;
  const int nblk0 = blockIdx.x * 4;

  const int arow = min(row0 + wave * 16 + n16, M - 1);
  half8 afrag[KS];
#pragma unroll
  for (int s = 0; s < KS; ++s)
    afrag[s] = *reinterpret_cast<const half8*>(A + (size_t)arow * K + s * 32 + quad * 8);

  floatx4 acc[4];
#pragma unroll
  for (int t = 0; t < 4; ++t) {
    acc[t] = (floatx4){0.f, 0.f, 0.f, 0.f};
#pragma unroll
    for (int s = 0; s < KS; ++s) {
      half8 bf = *reinterpret_cast<const half8*>(
          Wp + (((size_t)(nblk0 + t) * KS + s) * 64 + lane) * 8);
      acc[t] = __builtin_amdgcn_mfma_f32_16x16x32_f16(afrag[s], bf, acc[t], 0, 0, 0);
    }
  }

#pragma unroll
  for (int t = 0; t < 4; ++t) {
    float bv = bias[col0 + t * 16 + n16];
#pragma unroll
    for (int r = 0; r < 4; ++r)
      st[wave * 16 + quad * 4 + r][t * 16 + n16] = __float2half(acc[t][r] + bv);
  }
  __syncthreads();

  __half* dp;
  int colb, stride;
  if (col0 < HD + 64) {
    dp = QS; colb = col0; stride = QSS;
  } else if (col0 < 3 * HD + 64) {
    dp = KV; colb = col0 - HD - 64; stride = KVS;
  } else {
    dp = QS; colb = HD + 64 + (col0 - 3 * HD - 64); stride = QSS;
  }
  for (int c = tid; c < 512; c += 256) {
    int r = c >> 3, seg = c & 7;
    int row = row0 + r;
    if (row < M)
      *reinterpret_cast<uint4*>(dp + (size_t)row * stride + colb + seg * 8) =
          *reinterpret_cast<const uint4*>(&st[r][seg * 8]);
  }
}

// ---------------------------------------------------------------------------
// Pack weights into B-fragment order (f16), with fused G columns.
// ---------------------------------------------------------------------------
__device__ inline void pack_layer(int i, int K, int HD, int DOUT, float scale,
                                  const float* wq, const float* wk,
                                  const float* wv, const float* wsk,
                                  const float* we, const float* bq,
                                  const float* bk, const float* bv,
                                  const float* bs, __half* Wp, float* bcat) {
  const int W = 3 * HD + DOUT + 64;
  const int KS = K / 32;
  if (i < K * W) {
    int j = i & 7, lane = (i >> 3) & 63, fs = i >> 9;
    int nblk = fs / KS, s = fs - nblk * KS;
    int quad = lane >> 4, n = lane & 15;
    int k = s * 32 + quad * 8 + j, c = nblk * 16 + n;
    float v;
    if (c < HD) {
      v = wq[k * HD + c] * scale;
    } else if (c < HD + 64) {
      int gi = c - HD, hh = gi >> 4, d = gi & 15;
      float a = 0.f;
      for (int cc = 0; cc < DOUT; ++cc)
        a += wq[k * HD + hh * DOUT + cc] * we[d * HD + hh * DOUT + cc];
      v = a * scale;
    } else if (c < 2 * HD + 64) {
      v = wk[k * HD + (c - HD - 64)];
    } else if (c < 3 * HD + 64) {
      v = wv[k * HD + (c - 2 * HD - 64)];
    } else {
      v = wsk[k * DOUT + (c - 3 * HD - 64)];
    }
    Wp[i] = __float2half(v);
  } else {
    int c = i - K * W;
    float v;
    if (c < HD) {
      v = bq[c] * scale;
    } else if (c < HD + 64) {
      int gi = c - HD, hh = gi >> 4, d = gi & 15;
      float a = 0.f;
      for (int cc = 0; cc < DOUT; ++cc)
        a += bq[hh * DOUT + cc] * we[d * HD + hh * DOUT + cc];
      v = a * scale;
    } else if (c < 2 * HD + 64) {
      v = bk[c - HD - 64];
    } else if (c < 3 * HD + 64) {
      v = bv[c - 2 * HD - 64];
    } else {
      v = bs[c - 3 * HD - 64];
    }
    bcat[c] = v;
  }
}

#define T1 115584            // 128*896 + 896
#define T2 227904            // T1 + 64*1728 + 1728
#define T3 343488            // T2 + 128*896 + 896
#define TCONV (N_NODES * 32) // x float4 count
#define TTOT (T3 + TCONV)

__global__ void pack_all(
    const float* wq1, const float* wk1, const float* wv1, const float* ws1,
    const float* we1, const float* bq1, const float* bk1, const float* bv1,
    const float* bs1,
    const float* wq2, const float* wk2, const float* wv2, const float* ws2,
    const float* we2, const float* bq2, const float* bk2, const float* bv2,
    const float* bs2,
    const float* wq3, const float* wk3, const float* wv3, const float* ws3,
    const float* we3, const float* bq3, const float* bk3, const float* bv3,
    const float* bs3,
    __half* W1, float* b1, __half* W2, float* b2, __half* W3, float* b3,
    const float* x, __half* x16) {
  const float SC1 = 0.125f, SC2 = 0.08838834764831845f;
  for (int i = blockIdx.x * blockDim.x + threadIdx.x; i < TTOT;
       i += gridDim.x * blockDim.x) {
    if (i < T1)
      pack_layer(i, 128, 256, 64, SC1, wq1, wk1, wv1, ws1, we1, bq1, bk1, bv1, bs1, W1, b1);
    else if (i < T2)
      pack_layer(i - T1, 64, 512, 128, SC2, wq2, wk2, wv2, ws2, we2, bq2, bk2, bv2, bs2, W2, b2);
    else if (i < T3)
      pack_layer(i - T2, 128, 256, 64, SC1, wq3, wk3, wv3, ws3, we3, bq3, bk3, bv3, bs3, W3, b3);
    else {
      int k = i - T3;
      float4 v = reinterpret_cast<const float4*>(x)[k];
      __half2* o = reinterpret_cast<__half2*>(x16) + 2 * k;
      o[0] = __floats2half2_rn(v.x, v.y);
      o[1] = __floats2half2_rn(v.z, v.w);
    }
  }
}

// ---------------------------------------------------------------------------
// CSR build over dst
// ---------------------------------------------------------------------------
__global__ void count_dst(const int* __restrict__ dst, int* __restrict__ cnt) {
  int e = blockIdx.x * blockDim.x + threadIdx.x;
  if (e < N_EDGES) atomicAdd(&cnt[dst[e]], 1);
}

// Fused: exclusive scan of degrees -> offs, AND degree-descending counting
// sort of nodes -> perm (schedules heavy nodes first in edge_attn).
__global__ __launch_bounds__(1024) void scan_offs(const int* __restrict__ cnt,
                                                  int* __restrict__ offs,
                                                  int* __restrict__ perm) {
  __shared__ int part[1024];
  __shared__ int hist[256], hstart[256], hcur[256];
  const int t = threadIdx.x;
  const int chunk = (N_NODES + 1023) / 1024;
  const int b = t * chunk;
  const int e = min(N_NODES, b + chunk);
  if (t < 256) { hist[t] = 0; hcur[t] = 0; }
  __syncthreads();
  int s = 0;
  for (int i = b; i < e; ++i) {
    int d = cnt[i];
    s += d;
    atomicAdd(&hist[min(d, 255)], 1);
  }
  part[t] = s;
  __syncthreads();
  for (int off = 1; off < 1024; off <<= 1) {
    int v = (t >= off) ? part[t - off] : 0;
    __syncthreads();
    part[t] += v;
    __syncthreads();
  }
  if (t == 0) {
    int acc = 0;
    for (int bk = 255; bk >= 0; --bk) { hstart[bk] = acc; acc += hist[bk]; }
    offs[N_NODES] = part[1023];
  }
  __syncthreads();
  int pre = (t == 0) ? 0 : part[t - 1];
  for (int i = b; i < e; ++i) {
    offs[i] = pre;
    int d = cnt[i];
    pre += d;
    int bkt = min(d, 255);
    int pos = hstart[bkt] + atomicAdd(&hcur[bkt], 1);
    perm[pos] = i;
  }
}

__global__ void scatter_csr(const int* __restrict__ src, const int* __restrict__ dst,
                            const float* __restrict__ edge_attr,
                            const int* __restrict__ offs, int* __restrict__ cursor,
                            int* __restrict__ csr_src, float* __restrict__ csr_ea) {
  int e = blockIdx.x * blockDim.x + threadIdx.x;
  if (e < N_EDGES) {
    int d = dst[e];
    int pos = offs[d] + atomicAdd(&cursor[d], 1);
    csr_src[pos] = src[e];
    float4* o4 = reinterpret_cast<float4*>(csr_ea + (size_t)pos * 16);
    const float4* s4 = reinterpret_cast<const float4*>(edge_attr + (size_t)e * 16);
    o4[0] = s4[0]; o4[1] = s4[1]; o4[2] = s4[2]; o4[3] = s4[3];
  }
}

// ---------------------------------------------------------------------------
// Fused edge kernel (round-6 structure: 1 wave/node, ping-pong 4-edge groups,
// direct loads) + degree-sorted perm. 128-THREAD BLOCKS (2 nodes/block): the
// kernel has no LDS/syncthreads, so finer blocks give the scheduler 2x finer
// retirement/backfill granularity. W32: write f32 out (final layer only).
// ---------------------------------------------------------------------------
template <int DOUT, bool W32>
__global__ __launch_bounds__(128) void edge_attn(
    const __half* __restrict__ QS, const __half* __restrict__ KV,
    const float* __restrict__ we, const int* __restrict__ csr_src,
    const float* __restrict__ csr_ea, const int* __restrict__ offs,
    const int* __restrict__ perm, float* __restrict__ out,
    __half* __restrict__ out16) {
  constexpr int HD = 4 * DOUT;
  constexpr int QSS = HD + 64 + DOUT;
  constexpr int KVS = 2 * HD;
  constexpr int NV = DOUT / 64;
  using KWT = typename KW<NV>::T;

  const int lane = threadIdx.x & 63;
  const int h = lane >> 4, t16 = lane & 15;
  const int n = perm[blockIdx.x * 2 + (threadIdx.x >> 6)];  // N_NODES % 2 == 0
  const int c0 = t16 * 4 * NV;

  const __half* base = QS + (size_t)n * QSS;
  float4 q[NV], acc[NV];
  {
    KWT qw = *reinterpret_cast<const KWT*>(base + h * DOUT + c0);
    cvt_kv(qw, q);
  }
#pragma unroll
  for (int v = 0; v < NV; ++v) acc[v] = make_float4(0.f, 0.f, 0.f, 0.f);
  const float g = __half2float(base[HD + h * 16 + t16]);  // pre-scaled G

  float lsum = 0.f, tacc = 0.f;

  const int s0 = offs[n], s1 = offs[n + 1];

  int sjA[4], sjB[4];
  float eaA[4], eaB[4];
  KWT krA[4], vrA[4], krB[4], vrB[4];

  auto load_grp = [&](int bi, int (&sj)[4], float (&ea)[4], KWT (&kr)[4],
                      KWT (&vr)[4]) {
#pragma unroll
    for (int j = 0; j < 4; ++j) sj[j] = csr_src[bi + j];
#pragma unroll
    for (int j = 0; j < 4; ++j) ea[j] = csr_ea[(size_t)(bi + j) * 16 + t16];
#pragma unroll
    for (int j = 0; j < 4; ++j) {
      const __half* rb = KV + (size_t)sj[j] * KVS + h * DOUT + c0;
      kr[j] = *reinterpret_cast<const KWT*>(rb);
      vr[j] = *reinterpret_cast<const KWT*>(rb + HD);
    }
  };

  auto compute_grp = [&](float (&ea)[4], KWT (&kr)[4], KWT (&vr)[4]) {
    float a[4];
#pragma unroll
    for (int j = 0; j < 4; ++j) {
      float4 kk[NV];
      cvt_kv(kr[j], kk);
      float p = ea[j] * g;
#pragma unroll
      for (int v = 0; v < NV; ++v)
        p += q[v].x * kk[v].x + q[v].y * kk[v].y + q[v].z * kk[v].z +
             q[v].w * kk[v].w;
      a[j] = p;
    }
#pragma unroll
    for (int j = 0; j < 4; ++j) {
      a[j] += __shfl_xor(a[j], 1);
      a[j] += __shfl_xor(a[j], 2);
      a[j] += __shfl_xor(a[j], 4);
      a[j] += __shfl_xor(a[j], 8);
    }
    float p0 = __expf(a[0]), p1 = __expf(a[1]);
    float p2 = __expf(a[2]), p3 = __expf(a[3]);
    lsum += p0 + p1 + p2 + p3;
    tacc += p0 * ea[0] + p1 * ea[1] + p2 * ea[2] + p3 * ea[3];
    float pj[4] = {p0, p1, p2, p3};
#pragma unroll
    for (int j = 0; j < 4; ++j) {
      float4 vv[NV];
      cvt_kv(vr[j], vv);
#pragma unroll
      for (int v = 0; v < NV; ++v) {
        acc[v].x += pj[j] * vv[v].x;
        acc[v].y += pj[j] * vv[v].y;
        acc[v].z += pj[j] * vv[v].z;
        acc[v].w += pj[j] * vv[v].w;
      }
    }
  };

  int ii = s0;
  const int end_full = s0 + ((s1 - s0) & ~3);
  if (ii < end_full) {
    load_grp(ii, sjA, eaA, krA, vrA);
    for (;;) {
      int nx = ii + 4;
      if (nx >= end_full) { compute_grp(eaA, krA, vrA); ii = nx; break; }
      load_grp(nx, sjB, eaB, krB, vrB);
      compute_grp(eaA, krA, vrA);
      ii = nx; nx = ii + 4;
      if (nx >= end_full) { compute_grp(eaB, krB, vrB); ii = nx; break; }
      load_grp(nx, sjA, eaA, krA, vrA);
      compute_grp(eaB, krB, vrB);
      ii = nx;
    }
  }

  for (; ii < s1; ++ii) {
    int s = csr_src[ii];
    float ea0 = csr_ea[(size_t)ii * 16 + t16];
    const __half* rb = KV + (size_t)s * KVS + h * DOUT + c0;
    KWT kw = *reinterpret_cast<const KWT*>(rb);
    KWT vw = *reinterpret_cast<const KWT*>(rb + HD);
    float4 kk[NV], vv[NV];
    cvt_kv(kw, kk);
    cvt_kv(vw, vv);
    float a = ea0 * g;
#pragma unroll
    for (int v = 0; v < NV; ++v)
      a += q[v].x * kk[v].x + q[v].y * kk[v].y + q[v].z * kk[v].z + q[v].w * kk[v].w;
    a += __shfl_xor(a, 1);
    a += __shfl_xor(a, 2);
    a += __shfl_xor(a, 4);
    a += __shfl_xor(a, 8);
    float p = __expf(a);
    lsum += p;
    tacc += p * ea0;
#pragma unroll
    for (int v = 0; v < NV; ++v) {
      acc[v].x += p * vv[v].x;
      acc[v].y += p * vv[v].y;
      acc[v].z += p * vv[v].z;
      acc[v].w += p * vv[v].w;
    }
  }

  // epilogue: normalize, add (sum attn*ea)@we, head mean, skip, ELU
  float invl = (lsum > 0.f) ? 1.f / lsum : 0.f;
  float tn = tacc * invl;
  float4 val[NV];
#pragma unroll
  for (int v = 0; v < NV; ++v) {
    val[v].x = acc[v].x * invl; val[v].y = acc[v].y * invl;
    val[v].z = acc[v].z * invl; val[v].w = acc[v].w * invl;
  }
#pragma unroll
  for (int d = 0; d < 16; ++d) {
    float td = __shfl(tn, (lane & 48) | d);
    const float* wb = we + d * HD + h * DOUT + c0;
#pragma unroll
    for (int v = 0; v < NV; ++v) {
      float4 w4 = *reinterpret_cast<const float4*>(wb + 4 * v);
      val[v].x += td * w4.x; val[v].y += td * w4.y;
      val[v].z += td * w4.z; val[v].w += td * w4.w;
    }
  }
#pragma unroll
  for (int v = 0; v < NV; ++v) {
    val[v].x += __shfl_xor(val[v].x, 16); val[v].x += __shfl_xor(val[v].x, 32);
    val[v].y += __shfl_xor(val[v].y, 16); val[v].y += __shfl_xor(val[v].y, 32);
    val[v].z += __shfl_xor(val[v].z, 16); val[v].z += __shfl_xor(val[v].z, 32);
    val[v].w += __shfl_xor(val[v].w, 16); val[v].w += __shfl_xor(val[v].w, 32);
  }
  if (h == 0) {
    KWT sw = *reinterpret_cast<const KWT*>(base + HD + 64 + c0);
    float4 sk[NV];
    cvt_kv(sw, sk);
#pragma unroll
    for (int v = 0; v < NV; ++v) {
      float4 o;
      o.x = 0.25f * val[v].x + sk[v].x;
      o.y = 0.25f * val[v].y + sk[v].y;
      o.z = 0.25f * val[v].z + sk[v].z;
      o.w = 0.25f * val[v].w + sk[v].w;
      o.x = (o.x > 0.f) ? o.x : expm1f(o.x);
      o.y = (o.y > 0.f) ? o.y : expm1f(o.y);
      o.z = (o.z > 0.f) ? o.z : expm1f(o.z);
      o.w = (o.w > 0.f) ? o.w : expm1f(o.w);
      if (W32)
        *reinterpret_cast<float4*>(out + (size_t)n * DOUT + c0 + 4 * v) = o;
      __half2* o16 = reinterpret_cast<__half2*>(out16 + (size_t)n * DOUT + c0 + 4 * v);
      o16[0] = __floats2half2_rn(o.x, o.y);
      o16[1] = __floats2half2_rn(o.z, o.w);
    }
  }
}

// ---------------------------------------------------------------------------
// Global mean pool (batch sorted -> contiguous per-graph ranges)
// ---------------------------------------------------------------------------
__device__ inline int lower_bound(const int* b, int n, int v) {
  int lo = 0, hi = n;
  while (lo < hi) {
    int mid = (lo + hi) >> 1;
    if (b[mid] < v) lo = mid + 1; else hi = mid;
  }
  return lo;
}

__global__ __launch_bounds__(256) void pool_all(const float* __restrict__ h,
                                                const int* __restrict__ batch,
                                                float* __restrict__ out) {
  const int g = blockIdx.x;
  const int start = lower_bound(batch, N_NODES, g);
  const int end = lower_bound(batch, N_NODES, g + 1);
  const int c = threadIdx.x & 63, j = threadIdx.x >> 6;
  float s = 0.f;
  for (int n = start + j; n < end; n += 4) s += h[(size_t)n * 64 + c];
  __shared__ float red[4][64];
  red[j][c] = s;
  __syncthreads();
  if (j == 0) {
    float tot = red[0][c] + red[1][c] + red[2][c] + red[3][c];
    out[g * 64 + c] = tot / (float)max(end - start, 1);
  }
}

// ---------------------------------------------------------------------------
extern "C" void kernel_launch(void* const* d_in, const int* in_sizes, int n_in,
                              void* d_out, int out_size, void* d_ws, size_t ws_size,
                              hipStream_t stream) {
  const float* x = (const float*)d_in[0];
  const int* edge_index = (const int*)d_in[1];
  const float* edge_attr = (const float*)d_in[2];
  const int* batch = (const int*)d_in[3];
  const int* srcp = edge_index;
  const int* dstp = edge_index + N_EDGES;

  const bool dict_order = in_sizes[5] > 1024;
  const float *wq[3], *wk[3], *wv[3], *wep[3], *wsk[3], *bq[3], *bk[3], *bv[3], *bs[3];
  for (int L = 0; L < 3; ++L) {
    int b = 4 + L * 9;
    if (dict_order) {
      wq[L] = (const float*)d_in[b + 0];
      wk[L] = (const float*)d_in[b + 1];
      wv[L] = (const float*)d_in[b + 2];
      wep[L] = (const float*)d_in[b + 3];
      wsk[L] = (const float*)d_in[b + 4];
      bq[L] = (const float*)d_in[b + 5];
      bk[L] = (const float*)d_in[b + 6];
      bv[L] = (const float*)d_in[b + 7];
      bs[L] = (const float*)d_in[b + 8];
    } else {
      wq[L] = (const float*)d_in[b + 0];
      bq[L] = (const float*)d_in[b + 1];
      wk[L] = (const float*)d_in[b + 2];
      bk[L] = (const float*)d_in[b + 3];
      wv[L] = (const float*)d_in[b + 4];
      bv[L] = (const float*)d_in[b + 5];
      wep[L] = (const float*)d_in[b + 6];
      wsk[L] = (const float*)d_in[b + 7];
      bs[L] = (const float*)d_in[b + 8];
    }
  }

  // Workspace carve (bytes).
  char* p = (char*)d_ws;
  __half* qs = (__half*)p;    p += (size_t)N_NODES * 704 * 2;   // Q|G|S f16 (max L2)
  __half* kv = (__half*)p;    p += (size_t)N_NODES * 1024 * 2;  // K|V f16 (max L2)
  float* h1 = (float*)p;      p += (size_t)N_NODES * 64 * 4;
  __half* x16 = (__half*)p;   p += (size_t)N_NODES * 128 * 2;
  __half* h16 = (__half*)p;   p += (size_t)N_NODES * 128 * 2;
  __half* W1 = (__half*)p;    p += 128 * 896 * 2;
  __half* W2 = (__half*)p;    p += 64 * 1728 * 2;
  __half* W3 = (__half*)p;    p += 128 * 896 * 2;
  float* b1 = (float*)p;      p += 896 * 4;
  float* b2 = (float*)p;      p += 1728 * 4;
  float* b3 = (float*)p;      p += 896 * 4;
  float* csr_ea = (float*)p;  p += (size_t)N_EDGES * 16 * 4;
  int* cnt = (int*)p;         p += N_NODES * 4;
  int* cursor = (int*)p;      p += N_NODES * 4;
  int* offs = (int*)p;        p += (N_NODES + 1) * 4;
  int* perm = (int*)p;        p += N_NODES * 4;
  int* csr_src = (int*)p;     p += N_EDGES * 4;

  // ---- pack weights (f16 frag order, fused G cols) + x->f16 (1 launch) ----
  pack_all<<<1024, 256, 0, stream>>>(
      wq[0], wk[0], wv[0], wsk[0], wep[0], bq[0], bk[0], bv[0], bs[0],
      wq[1], wk[1], wv[1], wsk[1], wep[1], bq[1], bk[1], bv[1], bs[1],
      wq[2], wk[2], wv[2], wsk[2], wep[2], bq[2], bk[2], bv[2], bs[2],
      W1, b1, W2, b2, W3, b3, x, x16);

  // ---- CSR build over dst + degree-sorted scheduling permutation ----
  hipMemsetAsync(cnt, 0, 2 * N_NODES * sizeof(int), stream);  // cnt + cursor
  count_dst<<<(N_EDGES + 255) / 256, 256, 0, stream>>>(dstp, cnt);
  scan_offs<<<1, 1024, 0, stream>>>(cnt, offs, perm);
  scatter_csr<<<(N_EDGES + 255) / 256, 256, 0, stream>>>(srcp, dstp, edge_attr,
                                                         offs, cursor, csr_src, csr_ea);

  const int MT = (N_NODES + 63) / 64;
  // ---- layer 1: K=128, HD=256, DOUT=64 ----
  gemm_mfma<128, 256, 64><<<dim3(896 / 64, MT), 256, 0, stream>>>(x16, W1, b1, qs,
                                                                  kv, N_NODES);
  edge_attn<64, false><<<N_NODES / 2, 128, 0, stream>>>(qs, kv, wep[0], csr_src,
                                                        csr_ea, offs, perm, h1, h16);
  // ---- layer 2: K=64, HD=512, DOUT=128 ----
  gemm_mfma<64, 512, 128><<<dim3(1728 / 64, MT), 256, 0, stream>>>(h16, W2, b2, qs,
                                                                   kv, N_NODES);
  edge_attn<128, false><<<N_NODES / 2, 128, 0, stream>>>(qs, kv, wep[1], csr_src,
                                                         csr_ea, offs, perm, h1, h16);
  // ---- layer 3: K=128, HD=256, DOUT=64 ----
  gemm_mfma<128, 256, 64><<<dim3(896 / 64, MT), 256, 0, stream>>>(h16, W3, b3, qs,
                                                                  kv, N_NODES);
  edge_attn<64, true><<<N_NODES / 2, 128, 0, stream>>>(qs, kv, wep[2], csr_src,
                                                       csr_ea, offs, perm, h1, x16);

  // ---- global mean pool ----
  pool_all<<<N_GRAPHS, 256, 0, stream>>>(h1, batch, (float*)d_out);
}